// Round 9
// baseline (161.209 us; speedup 1.0000x reference)
//
#include <hip/hip_runtime.h>
#include <hip/hip_bf16.h>

typedef __hip_bfloat16 bf16;
typedef __attribute__((ext_vector_type(8))) short short8_t;
typedef __attribute__((ext_vector_type(4))) short short4_t;
typedef __attribute__((ext_vector_type(4))) float f32x4;

#define B_SZ   2
#define T_SEQ  2048
#define C_DIM  1024
#define NH     16
#define NKV    4
#define HD     64
#define QKVW   1536          // fused QKV row width (1024 Q | 256 K | 256 V)
#define MTOK   (B_SZ * T_SEQ)

#define LOG2_BASE_OVER_32 0.4152410118609203f
#define Q_SCALE 0.1803368801111204f   // 0.125 * log2(e)

__device__ __forceinline__ short f2bs(float f) {
    unsigned u = __float_as_uint(f);
    u += 0x7FFFu + ((u >> 16) & 1u);
    return (short)(u >> 16);
}
__device__ __forceinline__ short f2bs_trunc(float f) {
    return (short)(__float_as_uint(f) >> 16);
}
__device__ __forceinline__ float bs2f(short s) {
    unsigned u = ((unsigned)(unsigned short)s) << 16;
    return __uint_as_float(u);
}
// lane <-> lane^1 exchange, pure VALU (quad_perm [1,0,3,2])
__device__ __forceinline__ float dpp_xor1(float x) {
    return __int_as_float(
        __builtin_amdgcn_update_dpp(0, __float_as_int(x), 0xB1, 0xF, 0xF, true));
}
// bare v_exp_f32 (2^x)
__device__ __forceinline__ float fast_exp2(float x) {
    float r;
    asm("v_exp_f32 %0, %1" : "=v"(r) : "v"(x));
    return r;
}
// pack hi16(lo), hi16(hi) -> one dword (two bf16, truncating) in 1 v_perm_b32
__device__ __forceinline__ unsigned pack_bf16_trunc(float lo, float hi) {
    return __builtin_amdgcn_perm(__float_as_uint(hi), __float_as_uint(lo),
                                 0x07060302u);
}
// direct HBM -> LDS, 16B per lane. LDS dest = (wave-uniform base) + lane*16.
__device__ __forceinline__ void gload_lds16(const short* g, short* l) {
    __builtin_amdgcn_global_load_lds(
        (const __attribute__((address_space(1))) void*)g,
        (__attribute__((address_space(3))) void*)l, 16, 0, 0);
}

// ---------------------------------------------------------------------------
// Fused prep (unchanged): x->bf16, weight transposes, bias concat, RoPE table
// ---------------------------------------------------------------------------
__device__ __forceinline__ void transpose_tile(
    const float* __restrict__ W, short* __restrict__ Wt,
    int K, int N, int n0, int k0, int tid)
{
    __shared__ float tile[32][33];
    int tx = tid & 31, ty = tid >> 5;
    #pragma unroll
    for (int i = 0; i < 4; ++i)
        tile[ty + 8 * i][tx] = W[(size_t)(k0 + ty + 8 * i) * N + n0 + tx];
    __syncthreads();
    #pragma unroll
    for (int i = 0; i < 4; ++i)
        Wt[(size_t)(n0 + ty + 8 * i) * K + k0 + tx] = f2bs(tile[tx][ty + 8 * i]);
}

__global__ __launch_bounds__(256) void prep_kernel(
    const float* __restrict__ x,
    const float* __restrict__ w_q, const float* __restrict__ w_k,
    const float* __restrict__ w_v, const float* __restrict__ w_o,
    const float* __restrict__ b_q, const float* __restrict__ b_k,
    const float* __restrict__ b_v,
    short* __restrict__ Xb, short* __restrict__ Wqkv, short* __restrict__ Wto,
    float* __restrict__ Bqkv, float2* __restrict__ Tab)
{
    int blk = blockIdx.x, tid = threadIdx.x;
    if (blk < 4096) {
        int i = blk * 1024 + tid * 4;
        float4 v = *(const float4*)(x + i);
        short4_t o;
        o[0] = f2bs(v.x); o[1] = f2bs(v.y); o[2] = f2bs(v.z); o[3] = f2bs(v.w);
        *(short4_t*)(Xb + i) = o;
    } else if (blk < 5120) {
        int l = blk - 4096;
        transpose_tile(w_q, Wqkv, C_DIM, C_DIM, (l & 31) * 32, (l >> 5) * 32, tid);
    } else if (blk < 5376) {
        int l = blk - 5120;
        transpose_tile(w_k, Wqkv + (size_t)1024 * C_DIM, C_DIM, 256,
                       (l & 7) * 32, (l >> 3) * 32, tid);
    } else if (blk < 5632) {
        int l = blk - 5376;
        transpose_tile(w_v, Wqkv + (size_t)1280 * C_DIM, C_DIM, 256,
                       (l & 7) * 32, (l >> 3) * 32, tid);
    } else if (blk < 6656) {
        int l = blk - 5632;
        transpose_tile(w_o, Wto, C_DIM, C_DIM, (l & 31) * 32, (l >> 5) * 32, tid);
    } else if (blk < 6662) {
        int i = (blk - 6656) * 256 + tid;
        float v;
        if (i < 1024)      v = b_q[i];
        else if (i < 1280) v = b_k[i - 1024];
        else               v = b_v[i - 1280];
        Bqkv[i] = v;
    } else {
        int idx = (blk - 6662) * 256 + tid;
        int t = idx >> 5, i = idx & 31;
        float ang = (float)t * exp2f(-(float)i * LOG2_BASE_OVER_32);
        Tab[idx] = make_float2(cosf(ang), sinf(ang));
    }
}

// ---------------------------------------------------------------------------
// 128x128 GEMM K-loop building blocks (unchanged from R6): BK=64,
// global_load_lds staging, XOR-swizzled source + swizzled ds_read, 2-phase
// double-buffer with counted vmcnt(8).
// ---------------------------------------------------------------------------
#define GEMM_STAGE(dstA, dstB, Aptr, Bptr, k0)                                  \
    {                                                                           \
        _Pragma("unroll")                                                       \
        for (int it = 0; it < 4; ++it) {                                        \
            int i = (w * 4 + it) * 64 + lane;                                   \
            int row = i >> 3, p = i & 7;                                        \
            int gc = (k0) + ((p ^ (row & 7)) << 3);                             \
            gload_lds16((Aptr) + (size_t)(m0 + row) * K + gc,                   \
                        (dstA) + (w * 4 + it) * 512);                           \
        }                                                                       \
        _Pragma("unroll")                                                       \
        for (int it = 0; it < 4; ++it) {                                        \
            int i = (w * 4 + it) * 64 + lane;                                   \
            int row = i >> 3, p = i & 7;                                        \
            int gc = (k0) + ((p ^ (row & 7)) << 3);                             \
            gload_lds16((Bptr) + (size_t)(n0 + row) * K + gc,                   \
                        (dstB) + (w * 4 + it) * 512);                           \
        }                                                                       \
    }

#define GEMM_COMPUTE(srcA, srcB)                                                \
    {                                                                           \
        _Pragma("unroll")                                                       \
        for (int ks = 0; ks < 2; ++ks) {                                        \
            short8_t af[4], bf[4];                                              \
            _Pragma("unroll")                                                   \
            for (int mt = 0; mt < 4; ++mt) {                                    \
                int r = wm * 64 + mt * 16 + l16;                                \
                int g = ks * 4 + quad;                                          \
                af[mt] = *(const short8_t*)&(srcA)[r * 64 + ((g ^ (r & 7)) << 3)]; \
            }                                                                   \
            _Pragma("unroll")                                                   \
            for (int nt = 0; nt < 4; ++nt) {                                    \
                int r = wn * 64 + nt * 16 + l16;                                \
                int g = ks * 4 + quad;                                          \
                bf[nt] = *(const short8_t*)&(srcB)[r * 64 + ((g ^ (r & 7)) << 3)]; \
            }                                                                   \
            _Pragma("unroll")                                                   \
            for (int mt = 0; mt < 4; ++mt)                                      \
                _Pragma("unroll")                                               \
                for (int nt = 0; nt < 4; ++nt)                                  \
                    acc[mt][nt] = __builtin_amdgcn_mfma_f32_16x16x32_bf16(      \
                        af[mt], bf[nt], acc[mt][nt], 0, 0, 0);                  \
        }                                                                       \
    }

#define GEMM_KLOOP(Aptr, Bptr)                                                  \
    GEMM_STAGE(sA(0), sB(0), Aptr, Bptr, 0);                                    \
    for (int t = 0; t < NT; ++t) {                                              \
        int cur = t & 1;                                                        \
        if (t + 1 < NT) {                                                       \
            GEMM_STAGE(sA(cur ^ 1), sB(cur ^ 1), Aptr, Bptr, (t + 1) * 64);     \
            asm volatile("s_waitcnt vmcnt(8)" ::: "memory");                    \
        } else {                                                                \
            asm volatile("s_waitcnt vmcnt(0)" ::: "memory");                    \
        }                                                                       \
        __builtin_amdgcn_s_barrier();                                           \
        __builtin_amdgcn_sched_barrier(0);                                      \
        GEMM_COMPUTE(sA(cur), sB(cur));                                         \
        __builtin_amdgcn_sched_barrier(0);                                      \
        __builtin_amdgcn_s_barrier();                                           \
    }

// ---------------------------------------------------------------------------
// QKV GEMM (unchanged from R6): 128x128 tile, counted-vmcnt 2-phase.
// ---------------------------------------------------------------------------
__global__ __launch_bounds__(256) void gemm_qkv(
    const short* __restrict__ A, const short* __restrict__ Bt,
    const float* __restrict__ bias, const float2* __restrict__ Tab,
    short* __restrict__ QKVb, short* __restrict__ Vt)
{
    __shared__ __align__(16) short smem[32768];     // 64 KB: 2 x (A 8K | B 8K)
    #define sA(b) (smem + (b) * 16384)
    #define sB(b) (smem + (b) * 16384 + 8192)

    const int K = C_DIM, NT = C_DIM / 64;
    int m0 = blockIdx.y * 128;
    int n0 = blockIdx.x * 128;
    int tid  = threadIdx.x;
    int w    = tid >> 6, lane = tid & 63;
    int quad = lane >> 4, l16 = lane & 15;
    int wm = w & 1, wn = w >> 1;

    f32x4 acc[4][4] = {};

    GEMM_KLOOP(A, Bt);

    if (n0 < 1280) {
        // Q or K: bias + RoPE (+ Q_SCALE for Q)
        float scale = (n0 < 1024) ? Q_SCALE : 1.0f;
        float sgn   = (l16 & 1) ? 1.0f : -1.0f;
        #pragma unroll
        for (int nt = 0; nt < 4; ++nt) {
            int col = n0 + wn * 64 + nt * 16 + l16;
            int ip  = (col & 63) >> 1;
            float bv = bias[col];
            #pragma unroll
            for (int mt = 0; mt < 4; ++mt) {
                #pragma unroll
                for (int r = 0; r < 4; ++r) {
                    int row = m0 + wm * 64 + mt * 16 + quad * 4 + r;
                    float v = acc[mt][nt][r] + bv;
                    float po = dpp_xor1(v);
                    float2 cs = Tab[(row & (T_SEQ - 1)) * 32 + ip];
                    float res = (v * cs.x + sgn * po * cs.y) * scale;
                    QKVb[(size_t)row * QKVW + col] = f2bs(res);
                }
            }
        }
    } else {
        // V: bias + transpose -> Vt[d][token], two 64-dim passes through LDS
        short (*sT)[136] = (short(*)[136])smem;    // 64 x 136 shorts
        #pragma unroll
        for (int h2 = 0; h2 < 2; ++h2) {
            if (wn == h2) {
                #pragma unroll
                for (int nt = 0; nt < 4; ++nt) {
                    int col_l = nt * 16 + l16;             // 0..63
                    float bv = bias[n0 + h2 * 64 + col_l];
                    #pragma unroll
                    for (int mt = 0; mt < 4; ++mt)
                        #pragma unroll
                        for (int r = 0; r < 4; ++r)
                            sT[col_l][wm * 64 + mt * 16 + quad * 4 + r] =
                                f2bs(acc[mt][nt][r] + bv);
                }
            }
            __syncthreads();
            int d0 = n0 - 1280 + h2 * 64;
            #pragma unroll
            for (int it = 0; it < 4; ++it) {
                int slot = tid + 256 * it;                 // 64 dims x 16 segs
                int dl = slot >> 4, seg = (slot & 15) * 8;
                *(short8_t*)(Vt + (size_t)(d0 + dl) * MTOK + m0 + seg) =
                    *(const short8_t*)&sT[dl][seg];
            }
            __syncthreads();
        }
    }
    #undef sA
    #undef sB
}

// ---------------------------------------------------------------------------
// O-projection GEMM (unchanged from R6): 128x128 tile, counted-vmcnt 2-phase
// ---------------------------------------------------------------------------
__global__ __launch_bounds__(256) void gemm_mfma_o(
    const short* __restrict__ A, const short* __restrict__ Bt,
    const float* __restrict__ bias, float* __restrict__ C,
    int M, int N, int K_, int unused)
{
    __shared__ __align__(16) short smem[32768];
    #define sA(b) (smem + (b) * 16384)
    #define sB(b) (smem + (b) * 16384 + 8192)

    const int K = C_DIM, NT = C_DIM / 64;
    int m0 = blockIdx.y * 128;
    int n0 = blockIdx.x * 128;
    int tid  = threadIdx.x;
    int w    = tid >> 6, lane = tid & 63;
    int quad = lane >> 4, l16 = lane & 15;
    int wm = w & 1, wn = w >> 1;

    f32x4 acc[4][4] = {};

    GEMM_KLOOP(A, Bt);

    #pragma unroll
    for (int mt = 0; mt < 4; ++mt) {
        #pragma unroll
        for (int nt = 0; nt < 4; ++nt) {
            int col = n0 + wn * 64 + nt * 16 + l16;
            float bv = bias[col];
            #pragma unroll
            for (int r = 0; r < 4; ++r) {
                int row = m0 + wm * 64 + mt * 16 + quad * 4 + r;
                C[(size_t)row * N + col] = acc[mt][nt][r] + bv;
            }
        }
    }
    #undef sA
    #undef sB
}

// ---------------------------------------------------------------------------
// MFMA flash attention v16 = v15 + DEFERRED PV (T15 "compute cur / finish
// prev"). Region c now runs THREE overlapped streams between one barrier
// pair:   QK(c+1) [MFMA]  ∥  PV(c-1) [MFMA]  ∥  softmax(c) [VALU].
// The defer-max rescale (oacc *= al) sits after PV(c-1) in program order, so
// the register scoreboard guarantees it sees chunk c-1's accumulation —
// exactly what online softmax requires.
// V moves to 3 LDS buffers: region c reads sVt[(c-1)%3] (PV), writes V(c+1)
// into sVt[(c+1)%3]; the reused buffer ((c+1)≡(c-2) mod 3) was last read in
// region c-1, separated by barrier B_c. K stays 2-buffer DMA as in v15.
// pf carried one region (+8 VGPR). Epilogue runs the final PV(ct).
// ---------------------------------------------------------------------------
__global__ __launch_bounds__(512) void attn_mfma16(
    const short* __restrict__ QKV, const short* __restrict__ Vt,
    short* __restrict__ O)
{
    __shared__ __align__(16) short sK [2][64][64];   // swizzled granules
    __shared__ __align__(16) short sVt[3][64][72];   // padded, perm'd tokens

    const int tid  = threadIdx.x;          // 0..511
    const int w    = tid >> 6;             // 0..7
    const int lane = tid & 63;
    const int quad = lane >> 4;
    const int l16  = lane & 15;

    int blk = blockIdx.x;
    int grp = blk & 7;                     // (b,kvh)
    int pr  = 63 - (blk >> 3);             // pair index, long pairs first
    int kvh = grp & 3;
    int b   = grp >> 2;
    int h   = kvh * 4 + (w & 3);
    int tq  = pr * 2 + (w >> 2);           // waves 0-3: tile A, 4-7: tile B
    int ct  = pr >> 1;                     // == tq>>2 for both tiles
    int tg  = tq * 16 + l16;

    // Q frags (already roped + scaled)
    const short* qptr = QKV + ((size_t)(b * T_SEQ) + tq * 16 + l16) * QKVW + h * HD;
    short8_t qf0 = *(const short8_t*)(qptr + quad * 8);
    short8_t qf1 = *(const short8_t*)(qptr + quad * 8 + 32);

    const short* kbase  = QKV + (size_t)b * T_SEQ * QKVW + 1024 + kvh * HD;
    const short* vtbase = Vt + (size_t)(kvh * HD) * MTOK + b * T_SEQ;

    float m_l = -INFINITY, l_l = 0.f;      // quad-partial row sum
    f32x4 oacc[4];
    #pragma unroll
    for (int dt = 0; dt < 4; ++dt) oacc[dt] = (f32x4){0.f, 0.f, 0.f, 0.f};

    // K DMA staging indices (512 threads cover the 64x64 tile, 16B each)
    const int kr_  = tid >> 3;              // row 0..63
    const int kg   = tid & 7;               // dest granule
    const int ksrc = (kg ^ (kr_ & 7)) << 3; // pre-swizzled source col

    // V reg staging indices (512 threads cover the 64x64 tile)
    const int vdim = tid >> 3;              // 0..63
    const int s8   = tid & 7;
    const int vseg = s8 * 8;
    const int P0   = ((s8 & 4) << 3) | ((s8 & 1) << 4) | ((s8 & 2) << 1);

    // swizzled K read granule (row&7 == l16&7 since rows are l16+16kt)
    const int c0g = quad ^ (l16 & 7);

    // ---- prologue: K(0),V(0) staged; K(1) in flight; V(1) in vr; S(0) ----
    gload_lds16(kbase + (size_t)kr_ * QKVW + ksrc, (short*)sK[0] + (w << 9));
    {
        short8_t v0 = *(const short8_t*)(vtbase + (size_t)vdim * MTOK + vseg);
        union { short8_t v; short4_t h[2]; } u; u.v = v0;
        *(short4_t*)&sVt[0][vdim][P0]     = u.h[0];
        *(short4_t*)&sVt[0][vdim][P0 + 8] = u.h[1];
    }
    short8_t vr;
    if (ct > 0) {
        gload_lds16(kbase + (size_t)(64 + kr_) * QKVW + ksrc,
                    (short*)sK[1] + (w << 9));
        vr = *(const short8_t*)(vtbase + (size_t)vdim * MTOK + 64 + vseg);
    }
    __syncthreads();                        // K(0),V(0) visible; K(1) in flight

    f32x4 sacc[4], sacc_n[4];
    #pragma unroll
    for (int kt = 0; kt < 4; ++kt) {
        f32x4 z = {0.f, 0.f, 0.f, 0.f};
        const short* krow = &sK[0][l16 + 16 * kt][0];
        short8_t kf0 = *(const short8_t*)(krow + (c0g << 3));
        short8_t kf1 = *(const short8_t*)(krow + ((c0g ^ 4) << 3));
        z = __builtin_amdgcn_mfma_f32_16x16x32_bf16(kf0, qf0, z, 0, 0, 0);
        z = __builtin_amdgcn_mfma_f32_16x16x32_bf16(kf1, qf1, z, 0, 0, 0);
        sacc[kt] = z;
    }

    short8_t pf_prev0, pf_prev1;
    int vR = 2;                             // (c-1)%3 — PV read buffer
    int vW = 1;                             // (c+1)%3 — V write buffer

    for (int c = 0; c <= ct; ++c) {
        const int buf = c & 1;
        __syncthreads();                    // B_c: K(c+1) drained; V(c) visible

        __builtin_amdgcn_s_setprio(1);
        // stream 1: QK(c+1) — independent MFMA
        if (c < ct) {
            #pragma unroll
            for (int kt = 0; kt < 4; ++kt) {
                f32x4 z = {0.f, 0.f, 0.f, 0.f};
                const short* krow = &sK[buf ^ 1][l16 + 16 * kt][0];
                short8_t kf0 = *(const short8_t*)(krow + (c0g << 3));
                short8_t kf1 = *(const short8_t*)(krow + ((c0g ^ 4) << 3));
                z = __builtin_amdgcn_mfma_f32_16x16x32_bf16(kf0, qf0, z, 0, 0, 0);
                z = __builtin_amdgcn_mfma_f32_16x16x32_bf16(kf1, qf1, z, 0, 0, 0);
                sacc_n[kt] = z;
            }
            if (c + 2 <= ct) {
                int jn = (c + 2) * 64;
                gload_lds16(kbase + (size_t)(jn + kr_) * QKVW + ksrc,
                            (short*)sK[buf] + (w << 9));
            }
        }
        // stream 2: PV(c-1) — deferred from previous region
        if (c > 0) {
            #pragma unroll
            for (int dt = 0; dt < 4; ++dt) {
                short8_t vf0 = *(const short8_t*)&sVt[vR][16 * dt + l16][quad * 8];
                short8_t vf1 = *(const short8_t*)&sVt[vR][16 * dt + l16][quad * 8 + 32];
                oacc[dt] = __builtin_amdgcn_mfma_f32_16x16x32_bf16(pf_prev0, vf0, oacc[dt], 0, 0, 0);
                oacc[dt] = __builtin_amdgcn_mfma_f32_16x16x32_bf16(pf_prev1, vf1, oacc[dt], 0, 0, 0);
            }
        }
        __builtin_amdgcn_s_setprio(0);

        // stream 3: softmax(c) on sacc (VALU; overlaps the MFMAs above)
        if (c == ct) {
            int j0 = c * 64;
            #pragma unroll
            for (int kt = 0; kt < 4; ++kt)
                #pragma unroll
                for (int r = 0; r < 4; ++r)
                    if (j0 + 16 * kt + quad * 4 + r > tg) sacc[kt][r] = -INFINITY;
        }

        float v0 = fmaxf(fmaxf(sacc[0][0], sacc[0][1]), fmaxf(sacc[0][2], sacc[0][3]));
        float v1 = fmaxf(fmaxf(sacc[1][0], sacc[1][1]), fmaxf(sacc[1][2], sacc[1][3]));
        float v2 = fmaxf(fmaxf(sacc[2][0], sacc[2][1]), fmaxf(sacc[2][2], sacc[2][3]));
        float v3 = fmaxf(fmaxf(sacc[3][0], sacc[3][1]), fmaxf(sacc[3][2], sacc[3][3]));
        float vloc = fmaxf(fmaxf(v0, v1), fmaxf(v2, v3));

        if (!__all(vloc <= m_l + 8.0f)) {
            float vmax = fmaxf(vloc, __shfl_xor(vloc, 16));
            vmax = fmaxf(vmax, __shfl_xor(vmax, 32));
            float mnew = fmaxf(m_l, vmax);
            float al = fast_exp2(m_l - mnew);
            m_l = mnew;
            l_l *= al;
            // oacc RAW on PV(c-1) results — scoreboard orders this correctly
            #pragma unroll
            for (int r = 0; r < 4; ++r) {
                float alr = __shfl(al, quad * 4 + r);
                #pragma unroll
                for (int dt = 0; dt < 4; ++dt) oacc[dt][r] *= alr;
            }
        }

        float psum = 0.f;
        unsigned pk0, pk1, pk2, pk3, pk4, pk5, pk6, pk7;
        {
            float p0 = fast_exp2(sacc[0][0] - m_l), p1 = fast_exp2(sacc[0][1] - m_l);
            float p2 = fast_exp2(sacc[0][2] - m_l), p3 = fast_exp2(sacc[0][3] - m_l);
            psum += (p0 + p1) + (p2 + p3);
            pk0 = pack_bf16_trunc(p0, p1); pk1 = pack_bf16_trunc(p2, p3);
        }
        {
            float p0 = fast_exp2(sacc[1][0] - m_l), p1 = fast_exp2(sacc[1][1] - m_l);
            float p2 = fast_exp2(sacc[1][2] - m_l), p3 = fast_exp2(sacc[1][3] - m_l);
            psum += (p0 + p1) + (p2 + p3);
            pk2 = pack_bf16_trunc(p0, p1); pk3 = pack_bf16_trunc(p2, p3);
        }
        {
            float p0 = fast_exp2(sacc[2][0] - m_l), p1 = fast_exp2(sacc[2][1] - m_l);
            float p2 = fast_exp2(sacc[2][2] - m_l), p3 = fast_exp2(sacc[2][3] - m_l);
            psum += (p0 + p1) + (p2 + p3);
            pk4 = pack_bf16_trunc(p0, p1); pk5 = pack_bf16_trunc(p2, p3);
        }
        {
            float p0 = fast_exp2(sacc[3][0] - m_l), p1 = fast_exp2(sacc[3][1] - m_l);
            float p2 = fast_exp2(sacc[3][2] - m_l), p3 = fast_exp2(sacc[3][3] - m_l);
            psum += (p0 + p1) + (p2 + p3);
            pk6 = pack_bf16_trunc(p0, p1); pk7 = pack_bf16_trunc(p2, p3);
        }
        l_l += psum;

        {
            union { unsigned u[4]; short8_t v; } fa, fb;
            fa.u[0] = pk0; fa.u[1] = pk1; fa.u[2] = pk2; fa.u[3] = pk3;
            fb.u[0] = pk4; fb.u[1] = pk5; fb.u[2] = pk6; fb.u[3] = pk7;
            pf_prev0 = fa.v; pf_prev1 = fb.v;
        }

        // V(c+1) write + V(c+2) load issue
        if (c < ct) {
            union { short8_t v; short4_t hh[2]; } u; u.v = vr;
            *(short4_t*)&sVt[vW][vdim][P0]     = u.hh[0];
            *(short4_t*)&sVt[vW][vdim][P0 + 8] = u.hh[1];
            if (c + 2 <= ct)
                vr = *(const short8_t*)(vtbase + (size_t)vdim * MTOK
                                        + (c + 2) * 64 + vseg);
            // rotate S-tiles
            #pragma unroll
            for (int kt = 0; kt < 4; ++kt) sacc[kt] = sacc_n[kt];
        }

        vR = (vR == 2) ? 0 : vR + 1;
        vW = (vW == 2) ? 0 : vW + 1;
    }

    // epilogue: final PV(ct). sVt[ct%3] == sVt[vR] (vR advanced ct+1 times
    // from 2), written in region ct-1 (or prologue) — already visible.
    __builtin_amdgcn_s_setprio(1);
    #pragma unroll
    for (int dt = 0; dt < 4; ++dt) {
        short8_t vf0 = *(const short8_t*)&sVt[vR][16 * dt + l16][quad * 8];
        short8_t vf1 = *(const short8_t*)&sVt[vR][16 * dt + l16][quad * 8 + 32];
        oacc[dt] = __builtin_amdgcn_mfma_f32_16x16x32_bf16(pf_prev0, vf0, oacc[dt], 0, 0, 0);
        oacc[dt] = __builtin_amdgcn_mfma_f32_16x16x32_bf16(pf_prev1, vf1, oacc[dt], 0, 0, 0);
    }
    __builtin_amdgcn_s_setprio(0);

    l_l += __shfl_xor(l_l, 16);
    l_l += __shfl_xor(l_l, 32);

    #pragma unroll
    for (int r = 0; r < 4; ++r) {
        int m = quad * 4 + r;
        float lr = __shfl(l_l, quad * 4 + r);
        float inv = __builtin_amdgcn_rcpf(lr);
        #pragma unroll
        for (int dt = 0; dt < 4; ++dt)
            O[((size_t)b * T_SEQ + tq * 16 + m) * C_DIM + h * HD + 16 * dt + l16] =
                f2bs(oacc[dt][r] * inv);
    }
}

// ---------------------------------------------------------------------------
extern "C" void kernel_launch(void* const* d_in, const int* in_sizes, int n_in,
                              void* d_out, int out_size, void* d_ws, size_t ws_size,
                              hipStream_t stream)
{
    const float* x   = (const float*)d_in[0];
    const float* w_q = (const float*)d_in[1];
    const float* b_q = (const float*)d_in[2];
    const float* w_k = (const float*)d_in[3];
    const float* b_k = (const float*)d_in[4];
    const float* w_v = (const float*)d_in[5];
    const float* b_v = (const float*)d_in[6];
    const float* w_o = (const float*)d_in[7];
    const float* b_o = (const float*)d_in[8];
    float* out = (float*)d_out;

    char* ws = (char*)d_ws;
    short*  Xb   = (short*) (ws);                              // 8 MB
    short*  Ab   = (short*) (ws + ((size_t)8  << 20));         // 8 MB
    short*  QKVb = (short*) (ws + ((size_t)16 << 20));         // 12 MB
    short*  Wqkv = (short*) (ws + ((size_t)28 << 20));         // 3 MB
    short*  Wto  = (short*) (ws + ((size_t)31 << 20));         // 2 MB
    float*  Bqkv = (float*) (ws + ((size_t)33 << 20));         // 6 KB
    float2* Tab  = (float2*)(ws + ((size_t)33 << 20) + 8192);  // 512 KB
    short*  Vt   = (short*) (ws + ((size_t)34 << 20));         // 2 MB

    const int M = MTOK;   // 4096

    prep_kernel<<<6918, 256, 0, stream>>>(
        x, w_q, w_k, w_v, w_o, b_q, b_k, b_v, Xb, Wqkv, Wto, Bqkv, Tab);

    gemm_qkv<<<dim3(QKVW / 128, M / 128), 256, 0, stream>>>(
        Xb, Wqkv, Bqkv, Tab, QKVb, Vt);

    attn_mfma16<<<B_SZ * NKV * 64, 512, 0, stream>>>(QKVb, Vt, Ab);

    gemm_mfma_o<<<dim3(C_DIM / 128, M / 128), 256, 0, stream>>>(
        Ab, Wto, b_o, out, M, C_DIM, C_DIM, 0);
}

// Round 10
// 159.853 us; speedup vs baseline: 1.0085x; 1.0085x over previous
//
#include <hip/hip_runtime.h>
#include <hip/hip_bf16.h>

typedef __hip_bfloat16 bf16;
typedef __attribute__((ext_vector_type(8))) short short8_t;
typedef __attribute__((ext_vector_type(4))) short short4_t;
typedef __attribute__((ext_vector_type(4))) float f32x4;

#define B_SZ   2
#define T_SEQ  2048
#define C_DIM  1024
#define NH     16
#define NKV    4
#define HD     64
#define QKVW   1536          // fused QKV row width (1024 Q | 256 K | 256 V)
#define MTOK   (B_SZ * T_SEQ)

#define LOG2_BASE_OVER_32 0.4152410118609203f
#define Q_SCALE 0.1803368801111204f   // 0.125 * log2(e)

__device__ __forceinline__ short f2bs(float f) {
    unsigned u = __float_as_uint(f);
    u += 0x7FFFu + ((u >> 16) & 1u);
    return (short)(u >> 16);
}
__device__ __forceinline__ short f2bs_trunc(float f) {
    return (short)(__float_as_uint(f) >> 16);
}
__device__ __forceinline__ float bs2f(short s) {
    unsigned u = ((unsigned)(unsigned short)s) << 16;
    return __uint_as_float(u);
}
// lane <-> lane^1 exchange, pure VALU (quad_perm [1,0,3,2])
__device__ __forceinline__ float dpp_xor1(float x) {
    return __int_as_float(
        __builtin_amdgcn_update_dpp(0, __float_as_int(x), 0xB1, 0xF, 0xF, true));
}
// bare v_exp_f32 (2^x)
__device__ __forceinline__ float fast_exp2(float x) {
    float r;
    asm("v_exp_f32 %0, %1" : "=v"(r) : "v"(x));
    return r;
}
// pack hi16(lo), hi16(hi) -> one dword (two bf16, truncating) in 1 v_perm_b32
__device__ __forceinline__ unsigned pack_bf16_trunc(float lo, float hi) {
    return __builtin_amdgcn_perm(__float_as_uint(hi), __float_as_uint(lo),
                                 0x07060302u);
}
// direct HBM -> LDS, 16B per lane. LDS dest = (wave-uniform base) + lane*16.
__device__ __forceinline__ void gload_lds16(const short* g, short* l) {
    __builtin_amdgcn_global_load_lds(
        (const __attribute__((address_space(1))) void*)g,
        (__attribute__((address_space(3))) void*)l, 16, 0, 0);
}

// ---------------------------------------------------------------------------
// Fused prep (unchanged): x->bf16, weight transposes, bias concat, RoPE table
// ---------------------------------------------------------------------------
__device__ __forceinline__ void transpose_tile(
    const float* __restrict__ W, short* __restrict__ Wt,
    int K, int N, int n0, int k0, int tid)
{
    __shared__ float tile[32][33];
    int tx = tid & 31, ty = tid >> 5;
    #pragma unroll
    for (int i = 0; i < 4; ++i)
        tile[ty + 8 * i][tx] = W[(size_t)(k0 + ty + 8 * i) * N + n0 + tx];
    __syncthreads();
    #pragma unroll
    for (int i = 0; i < 4; ++i)
        Wt[(size_t)(n0 + ty + 8 * i) * K + k0 + tx] = f2bs(tile[tx][ty + 8 * i]);
}

__global__ __launch_bounds__(256) void prep_kernel(
    const float* __restrict__ x,
    const float* __restrict__ w_q, const float* __restrict__ w_k,
    const float* __restrict__ w_v, const float* __restrict__ w_o,
    const float* __restrict__ b_q, const float* __restrict__ b_k,
    const float* __restrict__ b_v,
    short* __restrict__ Xb, short* __restrict__ Wqkv, short* __restrict__ Wto,
    float* __restrict__ Bqkv, float2* __restrict__ Tab)
{
    int blk = blockIdx.x, tid = threadIdx.x;
    if (blk < 4096) {
        int i = blk * 1024 + tid * 4;
        float4 v = *(const float4*)(x + i);
        short4_t o;
        o[0] = f2bs(v.x); o[1] = f2bs(v.y); o[2] = f2bs(v.z); o[3] = f2bs(v.w);
        *(short4_t*)(Xb + i) = o;
    } else if (blk < 5120) {
        int l = blk - 4096;
        transpose_tile(w_q, Wqkv, C_DIM, C_DIM, (l & 31) * 32, (l >> 5) * 32, tid);
    } else if (blk < 5376) {
        int l = blk - 5120;
        transpose_tile(w_k, Wqkv + (size_t)1024 * C_DIM, C_DIM, 256,
                       (l & 7) * 32, (l >> 3) * 32, tid);
    } else if (blk < 5632) {
        int l = blk - 5376;
        transpose_tile(w_v, Wqkv + (size_t)1280 * C_DIM, C_DIM, 256,
                       (l & 7) * 32, (l >> 3) * 32, tid);
    } else if (blk < 6656) {
        int l = blk - 5632;
        transpose_tile(w_o, Wto, C_DIM, C_DIM, (l & 31) * 32, (l >> 5) * 32, tid);
    } else if (blk < 6662) {
        int i = (blk - 6656) * 256 + tid;
        float v;
        if (i < 1024)      v = b_q[i];
        else if (i < 1280) v = b_k[i - 1024];
        else               v = b_v[i - 1280];
        Bqkv[i] = v;
    } else {
        int idx = (blk - 6662) * 256 + tid;
        int t = idx >> 5, i = idx & 31;
        float ang = (float)t * exp2f(-(float)i * LOG2_BASE_OVER_32);
        Tab[idx] = make_float2(cosf(ang), sinf(ang));
    }
}

// ---------------------------------------------------------------------------
// 128x128 GEMM K-loop building blocks (unchanged from R6): BK=64,
// global_load_lds staging, XOR-swizzled source + swizzled ds_read, 2-phase
// double-buffer with counted vmcnt(8).
// ---------------------------------------------------------------------------
#define GEMM_STAGE(dstA, dstB, Aptr, Bptr, k0)                                  \
    {                                                                           \
        _Pragma("unroll")                                                       \
        for (int it = 0; it < 4; ++it) {                                        \
            int i = (w * 4 + it) * 64 + lane;                                   \
            int row = i >> 3, p = i & 7;                                        \
            int gc = (k0) + ((p ^ (row & 7)) << 3);                             \
            gload_lds16((Aptr) + (size_t)(m0 + row) * K + gc,                   \
                        (dstA) + (w * 4 + it) * 512);                           \
        }                                                                       \
        _Pragma("unroll")                                                       \
        for (int it = 0; it < 4; ++it) {                                        \
            int i = (w * 4 + it) * 64 + lane;                                   \
            int row = i >> 3, p = i & 7;                                        \
            int gc = (k0) + ((p ^ (row & 7)) << 3);                             \
            gload_lds16((Bptr) + (size_t)(n0 + row) * K + gc,                   \
                        (dstB) + (w * 4 + it) * 512);                           \
        }                                                                       \
    }

#define GEMM_COMPUTE(srcA, srcB)                                                \
    {                                                                           \
        _Pragma("unroll")                                                       \
        for (int ks = 0; ks < 2; ++ks) {                                        \
            short8_t af[4], bf[4];                                              \
            _Pragma("unroll")                                                   \
            for (int mt = 0; mt < 4; ++mt) {                                    \
                int r = wm * 64 + mt * 16 + l16;                                \
                int g = ks * 4 + quad;                                          \
                af[mt] = *(const short8_t*)&(srcA)[r * 64 + ((g ^ (r & 7)) << 3)]; \
            }                                                                   \
            _Pragma("unroll")                                                   \
            for (int nt = 0; nt < 4; ++nt) {                                    \
                int r = wn * 64 + nt * 16 + l16;                                \
                int g = ks * 4 + quad;                                          \
                bf[nt] = *(const short8_t*)&(srcB)[r * 64 + ((g ^ (r & 7)) << 3)]; \
            }                                                                   \
            _Pragma("unroll")                                                   \
            for (int mt = 0; mt < 4; ++mt)                                      \
                _Pragma("unroll")                                               \
                for (int nt = 0; nt < 4; ++nt)                                  \
                    acc[mt][nt] = __builtin_amdgcn_mfma_f32_16x16x32_bf16(      \
                        af[mt], bf[nt], acc[mt][nt], 0, 0, 0);                  \
        }                                                                       \
    }

#define GEMM_KLOOP(Aptr, Bptr)                                                  \
    GEMM_STAGE(sA(0), sB(0), Aptr, Bptr, 0);                                    \
    for (int t = 0; t < NT; ++t) {                                              \
        int cur = t & 1;                                                        \
        if (t + 1 < NT) {                                                       \
            GEMM_STAGE(sA(cur ^ 1), sB(cur ^ 1), Aptr, Bptr, (t + 1) * 64);     \
            asm volatile("s_waitcnt vmcnt(8)" ::: "memory");                    \
        } else {                                                                \
            asm volatile("s_waitcnt vmcnt(0)" ::: "memory");                    \
        }                                                                       \
        __builtin_amdgcn_s_barrier();                                           \
        __builtin_amdgcn_sched_barrier(0);                                      \
        GEMM_COMPUTE(sA(cur), sB(cur));                                         \
        __builtin_amdgcn_sched_barrier(0);                                      \
        __builtin_amdgcn_s_barrier();                                           \
    }

// ---------------------------------------------------------------------------
// QKV GEMM: 128x128 tile, counted-vmcnt 2-phase + T1 XCD-AWARE SWIZZLE.
// 1-D grid of 384 blocks; swz = (bid%8)*48 + bid/8 gives each XCD a
// contiguous 48-block chunk = 4 full A row-panels x all 12 col-blocks ->
// per-XCD L2 working set = 4 A-panels (1 MB) + B (3 MB); each A-panel is
// fetched by exactly ONE XCD (was: all 8).
// ---------------------------------------------------------------------------
__global__ __launch_bounds__(256) void gemm_qkv(
    const short* __restrict__ A, const short* __restrict__ Bt,
    const float* __restrict__ bias, const float2* __restrict__ Tab,
    short* __restrict__ QKVb, short* __restrict__ Vt)
{
    __shared__ __align__(16) short smem[32768];     // 64 KB: 2 x (A 8K | B 8K)
    #define sA(b) (smem + (b) * 16384)
    #define sB(b) (smem + (b) * 16384 + 8192)

    const int K = C_DIM, NT = C_DIM / 64;
    // XCD swizzle: 384 blocks, 48 per XCD, decode x-major (12 col-blocks)
    int bid = blockIdx.x;
    int swz = (bid & 7) * 48 + (bid >> 3);
    int m0 = (swz / 12) * 128;
    int n0 = (swz % 12) * 128;
    int tid  = threadIdx.x;
    int w    = tid >> 6, lane = tid & 63;
    int quad = lane >> 4, l16 = lane & 15;
    int wm = w & 1, wn = w >> 1;

    f32x4 acc[4][4] = {};

    GEMM_KLOOP(A, Bt);

    if (n0 < 1280) {
        // Q or K: bias + RoPE (+ Q_SCALE for Q)
        float scale = (n0 < 1024) ? Q_SCALE : 1.0f;
        float sgn   = (l16 & 1) ? 1.0f : -1.0f;
        #pragma unroll
        for (int nt = 0; nt < 4; ++nt) {
            int col = n0 + wn * 64 + nt * 16 + l16;
            int ip  = (col & 63) >> 1;
            float bv = bias[col];
            #pragma unroll
            for (int mt = 0; mt < 4; ++mt) {
                #pragma unroll
                for (int r = 0; r < 4; ++r) {
                    int row = m0 + wm * 64 + mt * 16 + quad * 4 + r;
                    float v = acc[mt][nt][r] + bv;
                    float po = dpp_xor1(v);
                    float2 cs = Tab[(row & (T_SEQ - 1)) * 32 + ip];
                    float res = (v * cs.x + sgn * po * cs.y) * scale;
                    QKVb[(size_t)row * QKVW + col] = f2bs(res);
                }
            }
        }
    } else {
        // V: bias + transpose -> Vt[d][token], two 64-dim passes through LDS
        short (*sT)[136] = (short(*)[136])smem;    // 64 x 136 shorts
        #pragma unroll
        for (int h2 = 0; h2 < 2; ++h2) {
            if (wn == h2) {
                #pragma unroll
                for (int nt = 0; nt < 4; ++nt) {
                    int col_l = nt * 16 + l16;             // 0..63
                    float bv = bias[n0 + h2 * 64 + col_l];
                    #pragma unroll
                    for (int mt = 0; mt < 4; ++mt)
                        #pragma unroll
                        for (int r = 0; r < 4; ++r)
                            sT[col_l][wm * 64 + mt * 16 + quad * 4 + r] =
                                f2bs(acc[mt][nt][r] + bv);
                }
            }
            __syncthreads();
            int d0 = n0 - 1280 + h2 * 64;
            #pragma unroll
            for (int it = 0; it < 4; ++it) {
                int slot = tid + 256 * it;                 // 64 dims x 16 segs
                int dl = slot >> 4, seg = (slot & 15) * 8;
                *(short8_t*)(Vt + (size_t)(d0 + dl) * MTOK + m0 + seg) =
                    *(const short8_t*)&sT[dl][seg];
            }
            __syncthreads();
        }
    }
    #undef sA
    #undef sB
}

// ---------------------------------------------------------------------------
// O-projection GEMM: 128x128 tile, counted-vmcnt 2-phase + XCD swizzle.
// 256 blocks, 32 per XCD = 4 A row-panels x all 8 col-blocks.
// ---------------------------------------------------------------------------
__global__ __launch_bounds__(256) void gemm_mfma_o(
    const short* __restrict__ A, const short* __restrict__ Bt,
    const float* __restrict__ bias, float* __restrict__ C,
    int M, int N, int K_, int unused)
{
    __shared__ __align__(16) short smem[32768];
    #define sA(b) (smem + (b) * 16384)
    #define sB(b) (smem + (b) * 16384 + 8192)

    const int K = C_DIM, NT = C_DIM / 64;
    int bid = blockIdx.x;
    int swz = (bid & 7) * 32 + (bid >> 3);
    int m0 = (swz >> 3) * 128;
    int n0 = (swz & 7) * 128;
    int tid  = threadIdx.x;
    int w    = tid >> 6, lane = tid & 63;
    int quad = lane >> 4, l16 = lane & 15;
    int wm = w & 1, wn = w >> 1;

    f32x4 acc[4][4] = {};

    GEMM_KLOOP(A, Bt);

    #pragma unroll
    for (int mt = 0; mt < 4; ++mt) {
        #pragma unroll
        for (int nt = 0; nt < 4; ++nt) {
            int col = n0 + wn * 64 + nt * 16 + l16;
            float bv = bias[col];
            #pragma unroll
            for (int r = 0; r < 4; ++r) {
                int row = m0 + wm * 64 + mt * 16 + quad * 4 + r;
                C[(size_t)row * N + col] = acc[mt][nt][r] + bv;
            }
        }
    }
    #undef sA
    #undef sB
}

// ---------------------------------------------------------------------------
// MFMA flash attention v15 (reverted from v16 — R8's measured best):
// 8-wave paired blocks, K-DMA staging, cross-chunk pipeline:
// QK^T(c+1) [MFMA] ∥ softmax(c) [VALU] between each barrier pair.
// ---------------------------------------------------------------------------
__global__ __launch_bounds__(512) void attn_mfma15(
    const short* __restrict__ QKV, const short* __restrict__ Vt,
    short* __restrict__ O)
{
    __shared__ __align__(16) short sK [2][64][64];   // swizzled granules, no pad
    __shared__ __align__(16) short sVt[2][64][72];   // padded, perm'd tokens

    const int tid  = threadIdx.x;          // 0..511
    const int w    = tid >> 6;             // 0..7
    const int lane = tid & 63;
    const int quad = lane >> 4;
    const int l16  = lane & 15;

    int blk = blockIdx.x;
    int grp = blk & 7;                     // (b,kvh)
    int pr  = 63 - (blk >> 3);             // pair index, long pairs first
    int kvh = grp & 3;
    int b   = grp >> 2;
    int h   = kvh * 4 + (w & 3);
    int tq  = pr * 2 + (w >> 2);           // waves 0-3: tile A, 4-7: tile B
    int ct  = pr >> 1;                     // == tq>>2 for both tiles
    int tg  = tq * 16 + l16;

    // Q frags (already roped + scaled)
    const short* qptr = QKV + ((size_t)(b * T_SEQ) + tq * 16 + l16) * QKVW + h * HD;
    short8_t qf0 = *(const short8_t*)(qptr + quad * 8);
    short8_t qf1 = *(const short8_t*)(qptr + quad * 8 + 32);

    const short* kbase  = QKV + (size_t)b * T_SEQ * QKVW + 1024 + kvh * HD;
    const short* vtbase = Vt + (size_t)(kvh * HD) * MTOK + b * T_SEQ;

    float m_l = -INFINITY, l_l = 0.f;      // quad-partial row sum
    f32x4 oacc[4];
    #pragma unroll
    for (int dt = 0; dt < 4; ++dt) oacc[dt] = (f32x4){0.f, 0.f, 0.f, 0.f};

    // K DMA staging indices (512 threads cover the 64x64 tile, 16B each)
    const int kr_  = tid >> 3;              // row 0..63
    const int kg   = tid & 7;               // dest granule
    const int ksrc = (kg ^ (kr_ & 7)) << 3; // pre-swizzled source col

    // V reg staging indices (512 threads cover the 64x64 tile)
    const int vdim = tid >> 3;              // 0..63
    const int s8   = tid & 7;
    const int vseg = s8 * 8;
    const int P0   = ((s8 & 4) << 3) | ((s8 & 1) << 4) | ((s8 & 2) << 1);

    // swizzled K read granule (row&7 == l16&7 since rows are l16+16kt)
    const int c0g = quad ^ (l16 & 7);

    // ---- prologue: K(0),V(0) staged; K(1) in flight; V(1) in vr; S(0) ----
    gload_lds16(kbase + (size_t)kr_ * QKVW + ksrc, (short*)sK[0] + (w << 9));
    {
        short8_t v0 = *(const short8_t*)(vtbase + (size_t)vdim * MTOK + vseg);
        union { short8_t v; short4_t h[2]; } u; u.v = v0;
        *(short4_t*)&sVt[0][vdim][P0]     = u.h[0];
        *(short4_t*)&sVt[0][vdim][P0 + 8] = u.h[1];
    }
    short8_t vr;
    if (ct > 0) {
        gload_lds16(kbase + (size_t)(64 + kr_) * QKVW + ksrc,
                    (short*)sK[1] + (w << 9));
        vr = *(const short8_t*)(vtbase + (size_t)vdim * MTOK + 64 + vseg);
    }
    __syncthreads();                        // K(0),V(0) visible; K(1) in flight

    f32x4 sacc[4], sacc_n[4];
    #pragma unroll
    for (int kt = 0; kt < 4; ++kt) {
        f32x4 z = {0.f, 0.f, 0.f, 0.f};
        const short* krow = &sK[0][l16 + 16 * kt][0];
        short8_t kf0 = *(const short8_t*)(krow + (c0g << 3));
        short8_t kf1 = *(const short8_t*)(krow + ((c0g ^ 4) << 3));
        z = __builtin_amdgcn_mfma_f32_16x16x32_bf16(kf0, qf0, z, 0, 0, 0);
        z = __builtin_amdgcn_mfma_f32_16x16x32_bf16(kf1, qf1, z, 0, 0, 0);
        sacc[kt] = z;
    }

    for (int c = 0; c <= ct; ++c) {
        const int buf = c & 1;
        __syncthreads();                    // B_c: K(c+1) drained, V(c) (and
                                            // V(c+1)-writes of R_{c-1}) visible

        __builtin_amdgcn_s_setprio(1);
        // QK(c+1): independent MFMA stream — interleaves with softmax(c) below
        if (c < ct) {
            #pragma unroll
            for (int kt = 0; kt < 4; ++kt) {
                f32x4 z = {0.f, 0.f, 0.f, 0.f};
                const short* krow = &sK[buf ^ 1][l16 + 16 * kt][0];
                short8_t kf0 = *(const short8_t*)(krow + (c0g << 3));
                short8_t kf1 = *(const short8_t*)(krow + ((c0g ^ 4) << 3));
                z = __builtin_amdgcn_mfma_f32_16x16x32_bf16(kf0, qf0, z, 0, 0, 0);
                z = __builtin_amdgcn_mfma_f32_16x16x32_bf16(kf1, qf1, z, 0, 0, 0);
                sacc_n[kt] = z;
            }
            if (c + 2 <= ct) {
                int jn = (c + 2) * 64;
                gload_lds16(kbase + (size_t)(jn + kr_) * QKVW + ksrc,
                            (short*)sK[buf] + (w << 9));
            }
        }

        // mask the CURRENT chunk's scores on the causal diagonal
        if (c == ct) {
            int j0 = c * 64;
            #pragma unroll
            for (int kt = 0; kt < 4; ++kt)
                #pragma unroll
                for (int r = 0; r < 4; ++r)
                    if (j0 + 16 * kt + quad * 4 + r > tg) sacc[kt][r] = -INFINITY;
        }

        // ---- softmax(c) on sacc (VALU; overlaps QK(c+1) MFMAs) ----
        float v0 = fmaxf(fmaxf(sacc[0][0], sacc[0][1]), fmaxf(sacc[0][2], sacc[0][3]));
        float v1 = fmaxf(fmaxf(sacc[1][0], sacc[1][1]), fmaxf(sacc[1][2], sacc[1][3]));
        float v2 = fmaxf(fmaxf(sacc[2][0], sacc[2][1]), fmaxf(sacc[2][2], sacc[2][3]));
        float v3 = fmaxf(fmaxf(sacc[3][0], sacc[3][1]), fmaxf(sacc[3][2], sacc[3][3]));
        float vloc = fmaxf(fmaxf(v0, v1), fmaxf(v2, v3));

        if (!__all(vloc <= m_l + 8.0f)) {
            float vmax = fmaxf(vloc, __shfl_xor(vloc, 16));
            vmax = fmaxf(vmax, __shfl_xor(vmax, 32));
            float mnew = fmaxf(m_l, vmax);
            float al = fast_exp2(m_l - mnew);
            m_l = mnew;
            l_l *= al;
            #pragma unroll
            for (int r = 0; r < 4; ++r) {
                float alr = __shfl(al, quad * 4 + r);
                #pragma unroll
                for (int dt = 0; dt < 4; ++dt) oacc[dt][r] *= alr;
            }
        }

        float psum = 0.f;
        unsigned pk0, pk1, pk2, pk3, pk4, pk5, pk6, pk7;
        {
            float p0 = fast_exp2(sacc[0][0] - m_l), p1 = fast_exp2(sacc[0][1] - m_l);
            float p2 = fast_exp2(sacc[0][2] - m_l), p3 = fast_exp2(sacc[0][3] - m_l);
            psum += (p0 + p1) + (p2 + p3);
            pk0 = pack_bf16_trunc(p0, p1); pk1 = pack_bf16_trunc(p2, p3);
        }
        {
            float p0 = fast_exp2(sacc[1][0] - m_l), p1 = fast_exp2(sacc[1][1] - m_l);
            float p2 = fast_exp2(sacc[1][2] - m_l), p3 = fast_exp2(sacc[1][3] - m_l);
            psum += (p0 + p1) + (p2 + p3);
            pk2 = pack_bf16_trunc(p0, p1); pk3 = pack_bf16_trunc(p2, p3);
        }
        {
            float p0 = fast_exp2(sacc[2][0] - m_l), p1 = fast_exp2(sacc[2][1] - m_l);
            float p2 = fast_exp2(sacc[2][2] - m_l), p3 = fast_exp2(sacc[2][3] - m_l);
            psum += (p0 + p1) + (p2 + p3);
            pk4 = pack_bf16_trunc(p0, p1); pk5 = pack_bf16_trunc(p2, p3);
        }
        {
            float p0 = fast_exp2(sacc[3][0] - m_l), p1 = fast_exp2(sacc[3][1] - m_l);
            float p2 = fast_exp2(sacc[3][2] - m_l), p3 = fast_exp2(sacc[3][3] - m_l);
            psum += (p0 + p1) + (p2 + p3);
            pk6 = pack_bf16_trunc(p0, p1); pk7 = pack_bf16_trunc(p2, p3);
        }
        l_l += psum;

        short8_t pf0, pf1;
        {
            union { unsigned u[4]; short8_t v; } fa, fb;
            fa.u[0] = pk0; fa.u[1] = pk1; fa.u[2] = pk2; fa.u[3] = pk3;
            fb.u[0] = pk4; fb.u[1] = pk5; fb.u[2] = pk6; fb.u[3] = pk7;
            pf0 = fa.v; pf1 = fb.v;
        }

        // V(c+1) write + V(c+2) load issue (hidden under PV)
        if (c < ct) {
            union { short8_t v; short4_t hh[2]; } u; u.v = vr;
            *(short4_t*)&sVt[buf ^ 1][vdim][P0]     = u.hh[0];
            *(short4_t*)&sVt[buf ^ 1][vdim][P0 + 8] = u.hh[1];
            if (c + 2 <= ct)
                vr = *(const short8_t*)(vtbase + (size_t)vdim * MTOK
                                        + (c + 2) * 64 + vseg);
        }

        // ---- PV(c) ----
        #pragma unroll
        for (int dt = 0; dt < 4; ++dt) {
            short8_t vf0 = *(const short8_t*)&sVt[buf][16 * dt + l16][quad * 8];
            short8_t vf1 = *(const short8_t*)&sVt[buf][16 * dt + l16][quad * 8 + 32];
            oacc[dt] = __builtin_amdgcn_mfma_f32_16x16x32_bf16(pf0, vf0, oacc[dt], 0, 0, 0);
            oacc[dt] = __builtin_amdgcn_mfma_f32_16x16x32_bf16(pf1, vf1, oacc[dt], 0, 0, 0);
        }
        __builtin_amdgcn_s_setprio(0);

        // rotate S-tiles
        #pragma unroll
        for (int kt = 0; kt < 4; ++kt) sacc[kt] = sacc_n[kt];
    }

    l_l += __shfl_xor(l_l, 16);
    l_l += __shfl_xor(l_l, 32);

    #pragma unroll
    for (int r = 0; r < 4; ++r) {
        int m = quad * 4 + r;
        float lr = __shfl(l_l, quad * 4 + r);
        float inv = __builtin_amdgcn_rcpf(lr);
        #pragma unroll
        for (int dt = 0; dt < 4; ++dt)
            O[((size_t)b * T_SEQ + tq * 16 + m) * C_DIM + h * HD + 16 * dt + l16] =
                f2bs(oacc[dt][r] * inv);
    }
}

// ---------------------------------------------------------------------------
extern "C" void kernel_launch(void* const* d_in, const int* in_sizes, int n_in,
                              void* d_out, int out_size, void* d_ws, size_t ws_size,
                              hipStream_t stream)
{
    const float* x   = (const float*)d_in[0];
    const float* w_q = (const float*)d_in[1];
    const float* b_q = (const float*)d_in[2];
    const float* w_k = (const float*)d_in[3];
    const float* b_k = (const float*)d_in[4];
    const float* w_v = (const float*)d_in[5];
    const float* b_v = (const float*)d_in[6];
    const float* w_o = (const float*)d_in[7];
    const float* b_o = (const float*)d_in[8];
    float* out = (float*)d_out;

    char* ws = (char*)d_ws;
    short*  Xb   = (short*) (ws);                              // 8 MB
    short*  Ab   = (short*) (ws + ((size_t)8  << 20));         // 8 MB
    short*  QKVb = (short*) (ws + ((size_t)16 << 20));         // 12 MB
    short*  Wqkv = (short*) (ws + ((size_t)28 << 20));         // 3 MB
    short*  Wto  = (short*) (ws + ((size_t)31 << 20));         // 2 MB
    float*  Bqkv = (float*) (ws + ((size_t)33 << 20));         // 6 KB
    float2* Tab  = (float2*)(ws + ((size_t)33 << 20) + 8192);  // 512 KB
    short*  Vt   = (short*) (ws + ((size_t)34 << 20));         // 2 MB

    const int M = MTOK;   // 4096

    prep_kernel<<<6918, 256, 0, stream>>>(
        x, w_q, w_k, w_v, w_o, b_q, b_k, b_v, Xb, Wqkv, Wto, Bqkv, Tab);

    gemm_qkv<<<384, 256, 0, stream>>>(
        Xb, Wqkv, Bqkv, Tab, QKVb, Vt);

    attn_mfma15<<<B_SZ * NKV * 64, 512, 0, stream>>>(QKVb, Vt, Ab);

    gemm_mfma_o<<<256, 256, 0, stream>>>(
        Ab, Wto, b_o, out, M, C_DIM, C_DIM, 0);
}

// Round 11
// 156.406 us; speedup vs baseline: 1.0307x; 1.0220x over previous
//
#include <hip/hip_runtime.h>
#include <hip/hip_bf16.h>

typedef __hip_bfloat16 bf16;
typedef __attribute__((ext_vector_type(8))) short short8_t;
typedef __attribute__((ext_vector_type(4))) short short4_t;
typedef __attribute__((ext_vector_type(4))) float f32x4;

#define B_SZ   2
#define T_SEQ  2048
#define C_DIM  1024
#define NH     16
#define NKV    4
#define HD     64
#define QKVW   1536          // fused QKV row width (1024 Q | 256 K | 256 V)
#define MTOK   (B_SZ * T_SEQ)

#define LOG2_BASE_OVER_32 0.4152410118609203f
#define Q_SCALE 0.1803368801111204f   // 0.125 * log2(e)

__device__ __forceinline__ short f2bs(float f) {
    unsigned u = __float_as_uint(f);
    u += 0x7FFFu + ((u >> 16) & 1u);
    return (short)(u >> 16);
}
__device__ __forceinline__ short f2bs_trunc(float f) {
    return (short)(__float_as_uint(f) >> 16);
}
__device__ __forceinline__ float bs2f(short s) {
    unsigned u = ((unsigned)(unsigned short)s) << 16;
    return __uint_as_float(u);
}
// lane <-> lane^1 exchange, pure VALU (quad_perm [1,0,3,2])
__device__ __forceinline__ float dpp_xor1(float x) {
    return __int_as_float(
        __builtin_amdgcn_update_dpp(0, __float_as_int(x), 0xB1, 0xF, 0xF, true));
}
// bare v_exp_f32 (2^x)
__device__ __forceinline__ float fast_exp2(float x) {
    float r;
    asm("v_exp_f32 %0, %1" : "=v"(r) : "v"(x));
    return r;
}
// pack hi16(lo), hi16(hi) -> one dword (two bf16, truncating) in 1 v_perm_b32
__device__ __forceinline__ unsigned pack_bf16_trunc(float lo, float hi) {
    return __builtin_amdgcn_perm(__float_as_uint(hi), __float_as_uint(lo),
                                 0x07060302u);
}
// direct HBM -> LDS, 16B per lane. LDS dest = (wave-uniform base) + lane*16.
__device__ __forceinline__ void gload_lds16(const short* g, short* l) {
    __builtin_amdgcn_global_load_lds(
        (const __attribute__((address_space(1))) void*)g,
        (__attribute__((address_space(3))) void*)l, 16, 0, 0);
}

// ---------------------------------------------------------------------------
// Fused prep (unchanged): x->bf16, weight transposes, bias concat, RoPE table
// ---------------------------------------------------------------------------
__device__ __forceinline__ void transpose_tile(
    const float* __restrict__ W, short* __restrict__ Wt,
    int K, int N, int n0, int k0, int tid)
{
    __shared__ float tile[32][33];
    int tx = tid & 31, ty = tid >> 5;
    #pragma unroll
    for (int i = 0; i < 4; ++i)
        tile[ty + 8 * i][tx] = W[(size_t)(k0 + ty + 8 * i) * N + n0 + tx];
    __syncthreads();
    #pragma unroll
    for (int i = 0; i < 4; ++i)
        Wt[(size_t)(n0 + ty + 8 * i) * K + k0 + tx] = f2bs(tile[tx][ty + 8 * i]);
}

__global__ __launch_bounds__(256) void prep_kernel(
    const float* __restrict__ x,
    const float* __restrict__ w_q, const float* __restrict__ w_k,
    const float* __restrict__ w_v, const float* __restrict__ w_o,
    const float* __restrict__ b_q, const float* __restrict__ b_k,
    const float* __restrict__ b_v,
    short* __restrict__ Xb, short* __restrict__ Wqkv, short* __restrict__ Wto,
    float* __restrict__ Bqkv, float2* __restrict__ Tab)
{
    int blk = blockIdx.x, tid = threadIdx.x;
    if (blk < 4096) {
        int i = blk * 1024 + tid * 4;
        float4 v = *(const float4*)(x + i);
        short4_t o;
        o[0] = f2bs(v.x); o[1] = f2bs(v.y); o[2] = f2bs(v.z); o[3] = f2bs(v.w);
        *(short4_t*)(Xb + i) = o;
    } else if (blk < 5120) {
        int l = blk - 4096;
        transpose_tile(w_q, Wqkv, C_DIM, C_DIM, (l & 31) * 32, (l >> 5) * 32, tid);
    } else if (blk < 5376) {
        int l = blk - 5120;
        transpose_tile(w_k, Wqkv + (size_t)1024 * C_DIM, C_DIM, 256,
                       (l & 7) * 32, (l >> 3) * 32, tid);
    } else if (blk < 5632) {
        int l = blk - 5376;
        transpose_tile(w_v, Wqkv + (size_t)1280 * C_DIM, C_DIM, 256,
                       (l & 7) * 32, (l >> 3) * 32, tid);
    } else if (blk < 6656) {
        int l = blk - 5632;
        transpose_tile(w_o, Wto, C_DIM, C_DIM, (l & 31) * 32, (l >> 5) * 32, tid);
    } else if (blk < 6662) {
        int i = (blk - 6656) * 256 + tid;
        float v;
        if (i < 1024)      v = b_q[i];
        else if (i < 1280) v = b_k[i - 1024];
        else               v = b_v[i - 1280];
        Bqkv[i] = v;
    } else {
        int idx = (blk - 6662) * 256 + tid;
        int t = idx >> 5, i = idx & 31;
        float ang = (float)t * exp2f(-(float)i * LOG2_BASE_OVER_32);
        Tab[idx] = make_float2(cosf(ang), sinf(ang));
    }
}

// ---------------------------------------------------------------------------
// 128x128 GEMM K-loop building blocks (unchanged from R6): BK=64,
// global_load_lds staging, XOR-swizzled source + swizzled ds_read, 2-phase
// double-buffer with counted vmcnt(8).
// ---------------------------------------------------------------------------
#define GEMM_STAGE(dstA, dstB, Aptr, Bptr, k0)                                  \
    {                                                                           \
        _Pragma("unroll")                                                       \
        for (int it = 0; it < 4; ++it) {                                        \
            int i = (w * 4 + it) * 64 + lane;                                   \
            int row = i >> 3, p = i & 7;                                        \
            int gc = (k0) + ((p ^ (row & 7)) << 3);                             \
            gload_lds16((Aptr) + (size_t)(m0 + row) * K + gc,                   \
                        (dstA) + (w * 4 + it) * 512);                           \
        }                                                                       \
        _Pragma("unroll")                                                       \
        for (int it = 0; it < 4; ++it) {                                        \
            int i = (w * 4 + it) * 64 + lane;                                   \
            int row = i >> 3, p = i & 7;                                        \
            int gc = (k0) + ((p ^ (row & 7)) << 3);                             \
            gload_lds16((Bptr) + (size_t)(n0 + row) * K + gc,                   \
                        (dstB) + (w * 4 + it) * 512);                           \
        }                                                                       \
    }

#define GEMM_COMPUTE(srcA, srcB)                                                \
    {                                                                           \
        _Pragma("unroll")                                                       \
        for (int ks = 0; ks < 2; ++ks) {                                        \
            short8_t af[4], bf[4];                                              \
            _Pragma("unroll")                                                   \
            for (int mt = 0; mt < 4; ++mt) {                                    \
                int r = wm * 64 + mt * 16 + l16;                                \
                int g = ks * 4 + quad;                                          \
                af[mt] = *(const short8_t*)&(srcA)[r * 64 + ((g ^ (r & 7)) << 3)]; \
            }                                                                   \
            _Pragma("unroll")                                                   \
            for (int nt = 0; nt < 4; ++nt) {                                    \
                int r = wn * 64 + nt * 16 + l16;                                \
                int g = ks * 4 + quad;                                          \
                bf[nt] = *(const short8_t*)&(srcB)[r * 64 + ((g ^ (r & 7)) << 3)]; \
            }                                                                   \
            _Pragma("unroll")                                                   \
            for (int mt = 0; mt < 4; ++mt)                                      \
                _Pragma("unroll")                                               \
                for (int nt = 0; nt < 4; ++nt)                                  \
                    acc[mt][nt] = __builtin_amdgcn_mfma_f32_16x16x32_bf16(      \
                        af[mt], bf[nt], acc[mt][nt], 0, 0, 0);                  \
        }                                                                       \
    }

#define GEMM_KLOOP(Aptr, Bptr)                                                  \
    GEMM_STAGE(sA(0), sB(0), Aptr, Bptr, 0);                                    \
    for (int t = 0; t < NT; ++t) {                                              \
        int cur = t & 1;                                                        \
        if (t + 1 < NT) {                                                       \
            GEMM_STAGE(sA(cur ^ 1), sB(cur ^ 1), Aptr, Bptr, (t + 1) * 64);     \
            asm volatile("s_waitcnt vmcnt(8)" ::: "memory");                    \
        } else {                                                                \
            asm volatile("s_waitcnt vmcnt(0)" ::: "memory");                    \
        }                                                                       \
        __builtin_amdgcn_s_barrier();                                           \
        __builtin_amdgcn_sched_barrier(0);                                      \
        GEMM_COMPUTE(sA(cur), sB(cur));                                         \
        __builtin_amdgcn_sched_barrier(0);                                      \
        __builtin_amdgcn_s_barrier();                                           \
    }

// ---------------------------------------------------------------------------
// QKV GEMM (unchanged from R10): 128x128 tile, counted-vmcnt 2-phase,
// XCD-aware block swizzle.
// ---------------------------------------------------------------------------
__global__ __launch_bounds__(256) void gemm_qkv(
    const short* __restrict__ A, const short* __restrict__ Bt,
    const float* __restrict__ bias, const float2* __restrict__ Tab,
    short* __restrict__ QKVb, short* __restrict__ Vt)
{
    __shared__ __align__(16) short smem[32768];     // 64 KB: 2 x (A 8K | B 8K)
    #define sA(b) (smem + (b) * 16384)
    #define sB(b) (smem + (b) * 16384 + 8192)

    const int K = C_DIM, NT = C_DIM / 64;
    // XCD swizzle: 384 blocks, 48 per XCD, decode x-major (12 col-blocks)
    int bid = blockIdx.x;
    int swz = (bid & 7) * 48 + (bid >> 3);
    int m0 = (swz / 12) * 128;
    int n0 = (swz % 12) * 128;
    int tid  = threadIdx.x;
    int w    = tid >> 6, lane = tid & 63;
    int quad = lane >> 4, l16 = lane & 15;
    int wm = w & 1, wn = w >> 1;

    f32x4 acc[4][4] = {};

    GEMM_KLOOP(A, Bt);

    if (n0 < 1280) {
        // Q or K: bias + RoPE (+ Q_SCALE for Q)
        float scale = (n0 < 1024) ? Q_SCALE : 1.0f;
        float sgn   = (l16 & 1) ? 1.0f : -1.0f;
        #pragma unroll
        for (int nt = 0; nt < 4; ++nt) {
            int col = n0 + wn * 64 + nt * 16 + l16;
            int ip  = (col & 63) >> 1;
            float bv = bias[col];
            #pragma unroll
            for (int mt = 0; mt < 4; ++mt) {
                #pragma unroll
                for (int r = 0; r < 4; ++r) {
                    int row = m0 + wm * 64 + mt * 16 + quad * 4 + r;
                    float v = acc[mt][nt][r] + bv;
                    float po = dpp_xor1(v);
                    float2 cs = Tab[(row & (T_SEQ - 1)) * 32 + ip];
                    float res = (v * cs.x + sgn * po * cs.y) * scale;
                    QKVb[(size_t)row * QKVW + col] = f2bs(res);
                }
            }
        }
    } else {
        // V: bias + transpose -> Vt[d][token], two 64-dim passes through LDS
        short (*sT)[136] = (short(*)[136])smem;    // 64 x 136 shorts
        #pragma unroll
        for (int h2 = 0; h2 < 2; ++h2) {
            if (wn == h2) {
                #pragma unroll
                for (int nt = 0; nt < 4; ++nt) {
                    int col_l = nt * 16 + l16;             // 0..63
                    float bv = bias[n0 + h2 * 64 + col_l];
                    #pragma unroll
                    for (int mt = 0; mt < 4; ++mt)
                        #pragma unroll
                        for (int r = 0; r < 4; ++r)
                            sT[col_l][wm * 64 + mt * 16 + quad * 4 + r] =
                                f2bs(acc[mt][nt][r] + bv);
                }
            }
            __syncthreads();
            int d0 = n0 - 1280 + h2 * 64;
            #pragma unroll
            for (int it = 0; it < 4; ++it) {
                int slot = tid + 256 * it;                 // 64 dims x 16 segs
                int dl = slot >> 4, seg = (slot & 15) * 8;
                *(short8_t*)(Vt + (size_t)(d0 + dl) * MTOK + m0 + seg) =
                    *(const short8_t*)&sT[dl][seg];
            }
            __syncthreads();
        }
    }
    #undef sA
    #undef sB
}

// ---------------------------------------------------------------------------
// O-projection GEMM (unchanged from R10): 128x128 tile, counted-vmcnt
// 2-phase, XCD swizzle.
// ---------------------------------------------------------------------------
__global__ __launch_bounds__(256) void gemm_mfma_o(
    const short* __restrict__ A, const short* __restrict__ Bt,
    const float* __restrict__ bias, float* __restrict__ C,
    int M, int N, int K_, int unused)
{
    __shared__ __align__(16) short smem[32768];
    #define sA(b) (smem + (b) * 16384)
    #define sB(b) (smem + (b) * 16384 + 8192)

    const int K = C_DIM, NT = C_DIM / 64;
    int bid = blockIdx.x;
    int swz = (bid & 7) * 32 + (bid >> 3);
    int m0 = (swz >> 3) * 128;
    int n0 = (swz & 7) * 128;
    int tid  = threadIdx.x;
    int w    = tid >> 6, lane = tid & 63;
    int quad = lane >> 4, l16 = lane & 15;
    int wm = w & 1, wn = w >> 1;

    f32x4 acc[4][4] = {};

    GEMM_KLOOP(A, Bt);

    #pragma unroll
    for (int mt = 0; mt < 4; ++mt) {
        #pragma unroll
        for (int nt = 0; nt < 4; ++nt) {
            int col = n0 + wn * 64 + nt * 16 + l16;
            float bv = bias[col];
            #pragma unroll
            for (int r = 0; r < 4; ++r) {
                int row = m0 + wm * 64 + mt * 16 + quad * 4 + r;
                C[(size_t)row * N + col] = acc[mt][nt][r] + bv;
            }
        }
    }
    #undef sA
    #undef sB
}

// ---------------------------------------------------------------------------
// MFMA flash attention v17 = v15 + ANTI-CORRELATED PAIR MAPPING.
// 512 blocks, exactly 2 resident per CU, no queue -> runtime is bound by the
// heaviest CU. Old mapping (pr = 63-(blk>>3)) paired blocks k and k+256 with
// region-sums ranging 18..49 across CUs (2.7x imbalance). New mapping gives
// the first 256 blocks the LONG pairs (pr 63..32) and the second 256 the
// SHORT pairs (pr 0..31): any {first-half, second-half} pairing sums to
// 31..35 regions — near-constant load on every CU. Same total work, grp
// (=blk&7) preserved, so co-resident blocks still share (b,kvh) K/V in L2.
// Kernel body identical to v15 (8-wave paired q-tiles, K-DMA staging,
// QK(c+1) MFMA ∥ softmax(c) VALU cross-chunk pipeline).
// ---------------------------------------------------------------------------
__global__ __launch_bounds__(512) void attn_mfma17(
    const short* __restrict__ QKV, const short* __restrict__ Vt,
    short* __restrict__ O)
{
    __shared__ __align__(16) short sK [2][64][64];   // swizzled granules, no pad
    __shared__ __align__(16) short sVt[2][64][72];   // padded, perm'd tokens

    const int tid  = threadIdx.x;          // 0..511
    const int w    = tid >> 6;             // 0..7
    const int lane = tid & 63;
    const int quad = lane >> 4;
    const int l16  = lane & 15;

    int blk = blockIdx.x;
    int grp = blk & 7;                     // (b,kvh)
    // anti-correlated pair mapping: first half long pairs, second half short
    int half = blk >> 8;                   // 0 or 1
    int idx8 = (blk & 255) >> 3;           // 0..31
    int pr   = half ? idx8 : 63 - idx8;    // [63..32] then [0..31]
    int kvh = grp & 3;
    int b   = grp >> 2;
    int h   = kvh * 4 + (w & 3);
    int tq  = pr * 2 + (w >> 2);           // waves 0-3: tile A, 4-7: tile B
    int ct  = pr >> 1;                     // == tq>>2 for both tiles
    int tg  = tq * 16 + l16;

    // Q frags (already roped + scaled)
    const short* qptr = QKV + ((size_t)(b * T_SEQ) + tq * 16 + l16) * QKVW + h * HD;
    short8_t qf0 = *(const short8_t*)(qptr + quad * 8);
    short8_t qf1 = *(const short8_t*)(qptr + quad * 8 + 32);

    const short* kbase  = QKV + (size_t)b * T_SEQ * QKVW + 1024 + kvh * HD;
    const short* vtbase = Vt + (size_t)(kvh * HD) * MTOK + b * T_SEQ;

    float m_l = -INFINITY, l_l = 0.f;      // quad-partial row sum
    f32x4 oacc[4];
    #pragma unroll
    for (int dt = 0; dt < 4; ++dt) oacc[dt] = (f32x4){0.f, 0.f, 0.f, 0.f};

    // K DMA staging indices (512 threads cover the 64x64 tile, 16B each)
    const int kr_  = tid >> 3;              // row 0..63
    const int kg   = tid & 7;               // dest granule
    const int ksrc = (kg ^ (kr_ & 7)) << 3; // pre-swizzled source col

    // V reg staging indices (512 threads cover the 64x64 tile)
    const int vdim = tid >> 3;              // 0..63
    const int s8   = tid & 7;
    const int vseg = s8 * 8;
    const int P0   = ((s8 & 4) << 3) | ((s8 & 1) << 4) | ((s8 & 2) << 1);

    // swizzled K read granule (row&7 == l16&7 since rows are l16+16kt)
    const int c0g = quad ^ (l16 & 7);

    // ---- prologue: K(0),V(0) staged; K(1) in flight; V(1) in vr; S(0) ----
    gload_lds16(kbase + (size_t)kr_ * QKVW + ksrc, (short*)sK[0] + (w << 9));
    {
        short8_t v0 = *(const short8_t*)(vtbase + (size_t)vdim * MTOK + vseg);
        union { short8_t v; short4_t h[2]; } u; u.v = v0;
        *(short4_t*)&sVt[0][vdim][P0]     = u.h[0];
        *(short4_t*)&sVt[0][vdim][P0 + 8] = u.h[1];
    }
    short8_t vr;
    if (ct > 0) {
        gload_lds16(kbase + (size_t)(64 + kr_) * QKVW + ksrc,
                    (short*)sK[1] + (w << 9));
        vr = *(const short8_t*)(vtbase + (size_t)vdim * MTOK + 64 + vseg);
    }
    __syncthreads();                        // K(0),V(0) visible; K(1) in flight

    f32x4 sacc[4], sacc_n[4];
    #pragma unroll
    for (int kt = 0; kt < 4; ++kt) {
        f32x4 z = {0.f, 0.f, 0.f, 0.f};
        const short* krow = &sK[0][l16 + 16 * kt][0];
        short8_t kf0 = *(const short8_t*)(krow + (c0g << 3));
        short8_t kf1 = *(const short8_t*)(krow + ((c0g ^ 4) << 3));
        z = __builtin_amdgcn_mfma_f32_16x16x32_bf16(kf0, qf0, z, 0, 0, 0);
        z = __builtin_amdgcn_mfma_f32_16x16x32_bf16(kf1, qf1, z, 0, 0, 0);
        sacc[kt] = z;
    }

    for (int c = 0; c <= ct; ++c) {
        const int buf = c & 1;
        __syncthreads();                    // B_c: K(c+1) drained, V(c) (and
                                            // V(c+1)-writes of R_{c-1}) visible

        __builtin_amdgcn_s_setprio(1);
        // QK(c+1): independent MFMA stream — interleaves with softmax(c) below
        if (c < ct) {
            #pragma unroll
            for (int kt = 0; kt < 4; ++kt) {
                f32x4 z = {0.f, 0.f, 0.f, 0.f};
                const short* krow = &sK[buf ^ 1][l16 + 16 * kt][0];
                short8_t kf0 = *(const short8_t*)(krow + (c0g << 3));
                short8_t kf1 = *(const short8_t*)(krow + ((c0g ^ 4) << 3));
                z = __builtin_amdgcn_mfma_f32_16x16x32_bf16(kf0, qf0, z, 0, 0, 0);
                z = __builtin_amdgcn_mfma_f32_16x16x32_bf16(kf1, qf1, z, 0, 0, 0);
                sacc_n[kt] = z;
            }
            if (c + 2 <= ct) {
                int jn = (c + 2) * 64;
                gload_lds16(kbase + (size_t)(jn + kr_) * QKVW + ksrc,
                            (short*)sK[buf] + (w << 9));
            }
        }

        // mask the CURRENT chunk's scores on the causal diagonal
        if (c == ct) {
            int j0 = c * 64;
            #pragma unroll
            for (int kt = 0; kt < 4; ++kt)
                #pragma unroll
                for (int r = 0; r < 4; ++r)
                    if (j0 + 16 * kt + quad * 4 + r > tg) sacc[kt][r] = -INFINITY;
        }

        // ---- softmax(c) on sacc (VALU; overlaps QK(c+1) MFMAs) ----
        float v0 = fmaxf(fmaxf(sacc[0][0], sacc[0][1]), fmaxf(sacc[0][2], sacc[0][3]));
        float v1 = fmaxf(fmaxf(sacc[1][0], sacc[1][1]), fmaxf(sacc[1][2], sacc[1][3]));
        float v2 = fmaxf(fmaxf(sacc[2][0], sacc[2][1]), fmaxf(sacc[2][2], sacc[2][3]));
        float v3 = fmaxf(fmaxf(sacc[3][0], sacc[3][1]), fmaxf(sacc[3][2], sacc[3][3]));
        float vloc = fmaxf(fmaxf(v0, v1), fmaxf(v2, v3));

        if (!__all(vloc <= m_l + 8.0f)) {
            float vmax = fmaxf(vloc, __shfl_xor(vloc, 16));
            vmax = fmaxf(vmax, __shfl_xor(vmax, 32));
            float mnew = fmaxf(m_l, vmax);
            float al = fast_exp2(m_l - mnew);
            m_l = mnew;
            l_l *= al;
            #pragma unroll
            for (int r = 0; r < 4; ++r) {
                float alr = __shfl(al, quad * 4 + r);
                #pragma unroll
                for (int dt = 0; dt < 4; ++dt) oacc[dt][r] *= alr;
            }
        }

        float psum = 0.f;
        unsigned pk0, pk1, pk2, pk3, pk4, pk5, pk6, pk7;
        {
            float p0 = fast_exp2(sacc[0][0] - m_l), p1 = fast_exp2(sacc[0][1] - m_l);
            float p2 = fast_exp2(sacc[0][2] - m_l), p3 = fast_exp2(sacc[0][3] - m_l);
            psum += (p0 + p1) + (p2 + p3);
            pk0 = pack_bf16_trunc(p0, p1); pk1 = pack_bf16_trunc(p2, p3);
        }
        {
            float p0 = fast_exp2(sacc[1][0] - m_l), p1 = fast_exp2(sacc[1][1] - m_l);
            float p2 = fast_exp2(sacc[1][2] - m_l), p3 = fast_exp2(sacc[1][3] - m_l);
            psum += (p0 + p1) + (p2 + p3);
            pk2 = pack_bf16_trunc(p0, p1); pk3 = pack_bf16_trunc(p2, p3);
        }
        {
            float p0 = fast_exp2(sacc[2][0] - m_l), p1 = fast_exp2(sacc[2][1] - m_l);
            float p2 = fast_exp2(sacc[2][2] - m_l), p3 = fast_exp2(sacc[2][3] - m_l);
            psum += (p0 + p1) + (p2 + p3);
            pk4 = pack_bf16_trunc(p0, p1); pk5 = pack_bf16_trunc(p2, p3);
        }
        {
            float p0 = fast_exp2(sacc[3][0] - m_l), p1 = fast_exp2(sacc[3][1] - m_l);
            float p2 = fast_exp2(sacc[3][2] - m_l), p3 = fast_exp2(sacc[3][3] - m_l);
            psum += (p0 + p1) + (p2 + p3);
            pk6 = pack_bf16_trunc(p0, p1); pk7 = pack_bf16_trunc(p2, p3);
        }
        l_l += psum;

        short8_t pf0, pf1;
        {
            union { unsigned u[4]; short8_t v; } fa, fb;
            fa.u[0] = pk0; fa.u[1] = pk1; fa.u[2] = pk2; fa.u[3] = pk3;
            fb.u[0] = pk4; fb.u[1] = pk5; fb.u[2] = pk6; fb.u[3] = pk7;
            pf0 = fa.v; pf1 = fb.v;
        }

        // V(c+1) write + V(c+2) load issue (hidden under PV)
        if (c < ct) {
            union { short8_t v; short4_t hh[2]; } u; u.v = vr;
            *(short4_t*)&sVt[buf ^ 1][vdim][P0]     = u.hh[0];
            *(short4_t*)&sVt[buf ^ 1][vdim][P0 + 8] = u.hh[1];
            if (c + 2 <= ct)
                vr = *(const short8_t*)(vtbase + (size_t)vdim * MTOK
                                        + (c + 2) * 64 + vseg);
        }

        // ---- PV(c) ----
        #pragma unroll
        for (int dt = 0; dt < 4; ++dt) {
            short8_t vf0 = *(const short8_t*)&sVt[buf][16 * dt + l16][quad * 8];
            short8_t vf1 = *(const short8_t*)&sVt[buf][16 * dt + l16][quad * 8 + 32];
            oacc[dt] = __builtin_amdgcn_mfma_f32_16x16x32_bf16(pf0, vf0, oacc[dt], 0, 0, 0);
            oacc[dt] = __builtin_amdgcn_mfma_f32_16x16x32_bf16(pf1, vf1, oacc[dt], 0, 0, 0);
        }
        __builtin_amdgcn_s_setprio(0);

        // rotate S-tiles
        #pragma unroll
        for (int kt = 0; kt < 4; ++kt) sacc[kt] = sacc_n[kt];
    }

    l_l += __shfl_xor(l_l, 16);
    l_l += __shfl_xor(l_l, 32);

    #pragma unroll
    for (int r = 0; r < 4; ++r) {
        int m = quad * 4 + r;
        float lr = __shfl(l_l, quad * 4 + r);
        float inv = __builtin_amdgcn_rcpf(lr);
        #pragma unroll
        for (int dt = 0; dt < 4; ++dt)
            O[((size_t)b * T_SEQ + tq * 16 + m) * C_DIM + h * HD + 16 * dt + l16] =
                f2bs(oacc[dt][r] * inv);
    }
}

// ---------------------------------------------------------------------------
extern "C" void kernel_launch(void* const* d_in, const int* in_sizes, int n_in,
                              void* d_out, int out_size, void* d_ws, size_t ws_size,
                              hipStream_t stream)
{
    const float* x   = (const float*)d_in[0];
    const float* w_q = (const float*)d_in[1];
    const float* b_q = (const float*)d_in[2];
    const float* w_k = (const float*)d_in[3];
    const float* b_k = (const float*)d_in[4];
    const float* w_v = (const float*)d_in[5];
    const float* b_v = (const float*)d_in[6];
    const float* w_o = (const float*)d_in[7];
    const float* b_o = (const float*)d_in[8];
    float* out = (float*)d_out;

    char* ws = (char*)d_ws;
    short*  Xb   = (short*) (ws);                              // 8 MB
    short*  Ab   = (short*) (ws + ((size_t)8  << 20));         // 8 MB
    short*  QKVb = (short*) (ws + ((size_t)16 << 20));         // 12 MB
    short*  Wqkv = (short*) (ws + ((size_t)28 << 20));         // 3 MB
    short*  Wto  = (short*) (ws + ((size_t)31 << 20));         // 2 MB
    float*  Bqkv = (float*) (ws + ((size_t)33 << 20));         // 6 KB
    float2* Tab  = (float2*)(ws + ((size_t)33 << 20) + 8192);  // 512 KB
    short*  Vt   = (short*) (ws + ((size_t)34 << 20));         // 2 MB

    const int M = MTOK;   // 4096

    prep_kernel<<<6918, 256, 0, stream>>>(
        x, w_q, w_k, w_v, w_o, b_q, b_k, b_v, Xb, Wqkv, Wto, Bqkv, Tab);

    gemm_qkv<<<384, 256, 0, stream>>>(
        Xb, Wqkv, Bqkv, Tab, QKVb, Vt);

    attn_mfma17<<<B_SZ * NKV * 64, 512, 0, stream>>>(QKVb, Vt, Ab);

    gemm_mfma_o<<<256, 256, 0, stream>>>(
        Ab, Wto, b_o, out, M, C_DIM, C_DIM, 0);
}

// Round 12
// 155.233 us; speedup vs baseline: 1.0385x; 1.0076x over previous
//
#include <hip/hip_runtime.h>
#include <hip/hip_bf16.h>

typedef __hip_bfloat16 bf16;
typedef __attribute__((ext_vector_type(8))) short short8_t;
typedef __attribute__((ext_vector_type(4))) short short4_t;
typedef __attribute__((ext_vector_type(4))) float f32x4;

#define B_SZ   2
#define T_SEQ  2048
#define C_DIM  1024
#define NH     16
#define NKV    4
#define HD     64
#define QKVW   1536          // fused QKV row width (1024 Q | 256 K | 256 V)
#define MTOK   (B_SZ * T_SEQ)

#define LOG2_BASE_OVER_32 0.4152410118609203f
#define Q_SCALE 0.1803368801111204f   // 0.125 * log2(e)

__device__ __forceinline__ short f2bs(float f) {
    unsigned u = __float_as_uint(f);
    u += 0x7FFFu + ((u >> 16) & 1u);
    return (short)(u >> 16);
}
__device__ __forceinline__ short f2bs_trunc(float f) {
    return (short)(__float_as_uint(f) >> 16);
}
__device__ __forceinline__ float bs2f(short s) {
    unsigned u = ((unsigned)(unsigned short)s) << 16;
    return __uint_as_float(u);
}
// lane <-> lane^1 exchange, pure VALU (quad_perm [1,0,3,2])
__device__ __forceinline__ float dpp_xor1(float x) {
    return __int_as_float(
        __builtin_amdgcn_update_dpp(0, __float_as_int(x), 0xB1, 0xF, 0xF, true));
}
// bare v_exp_f32 (2^x)
__device__ __forceinline__ float fast_exp2(float x) {
    float r;
    asm("v_exp_f32 %0, %1" : "=v"(r) : "v"(x));
    return r;
}
// pack hi16(lo), hi16(hi) -> one dword (two bf16, truncating) in 1 v_perm_b32
__device__ __forceinline__ unsigned pack_bf16_trunc(float lo, float hi) {
    return __builtin_amdgcn_perm(__float_as_uint(hi), __float_as_uint(lo),
                                 0x07060302u);
}
// direct HBM -> LDS, 16B per lane. LDS dest = (wave-uniform base) + lane*16.
__device__ __forceinline__ void gload_lds16(const short* g, short* l) {
    __builtin_amdgcn_global_load_lds(
        (const __attribute__((address_space(1))) void*)g,
        (__attribute__((address_space(3))) void*)l, 16, 0, 0);
}

// ---------------------------------------------------------------------------
// Fused prep (unchanged): x->bf16, weight transposes, bias concat, RoPE table
// ---------------------------------------------------------------------------
__device__ __forceinline__ void transpose_tile(
    const float* __restrict__ W, short* __restrict__ Wt,
    int K, int N, int n0, int k0, int tid)
{
    __shared__ float tile[32][33];
    int tx = tid & 31, ty = tid >> 5;
    #pragma unroll
    for (int i = 0; i < 4; ++i)
        tile[ty + 8 * i][tx] = W[(size_t)(k0 + ty + 8 * i) * N + n0 + tx];
    __syncthreads();
    #pragma unroll
    for (int i = 0; i < 4; ++i)
        Wt[(size_t)(n0 + ty + 8 * i) * K + k0 + tx] = f2bs(tile[tx][ty + 8 * i]);
}

__global__ __launch_bounds__(256) void prep_kernel(
    const float* __restrict__ x,
    const float* __restrict__ w_q, const float* __restrict__ w_k,
    const float* __restrict__ w_v, const float* __restrict__ w_o,
    const float* __restrict__ b_q, const float* __restrict__ b_k,
    const float* __restrict__ b_v,
    short* __restrict__ Xb, short* __restrict__ Wqkv, short* __restrict__ Wto,
    float* __restrict__ Bqkv, float2* __restrict__ Tab)
{
    int blk = blockIdx.x, tid = threadIdx.x;
    if (blk < 4096) {
        int i = blk * 1024 + tid * 4;
        float4 v = *(const float4*)(x + i);
        short4_t o;
        o[0] = f2bs(v.x); o[1] = f2bs(v.y); o[2] = f2bs(v.z); o[3] = f2bs(v.w);
        *(short4_t*)(Xb + i) = o;
    } else if (blk < 5120) {
        int l = blk - 4096;
        transpose_tile(w_q, Wqkv, C_DIM, C_DIM, (l & 31) * 32, (l >> 5) * 32, tid);
    } else if (blk < 5376) {
        int l = blk - 5120;
        transpose_tile(w_k, Wqkv + (size_t)1024 * C_DIM, C_DIM, 256,
                       (l & 7) * 32, (l >> 3) * 32, tid);
    } else if (blk < 5632) {
        int l = blk - 5376;
        transpose_tile(w_v, Wqkv + (size_t)1280 * C_DIM, C_DIM, 256,
                       (l & 7) * 32, (l >> 3) * 32, tid);
    } else if (blk < 6656) {
        int l = blk - 5632;
        transpose_tile(w_o, Wto, C_DIM, C_DIM, (l & 31) * 32, (l >> 5) * 32, tid);
    } else if (blk < 6662) {
        int i = (blk - 6656) * 256 + tid;
        float v;
        if (i < 1024)      v = b_q[i];
        else if (i < 1280) v = b_k[i - 1024];
        else               v = b_v[i - 1280];
        Bqkv[i] = v;
    } else {
        int idx = (blk - 6662) * 256 + tid;
        int t = idx >> 5, i = idx & 31;
        float ang = (float)t * exp2f(-(float)i * LOG2_BASE_OVER_32);
        Tab[idx] = make_float2(cosf(ang), sinf(ang));
    }
}

// ---------------------------------------------------------------------------
// 128x128 GEMM K-loop building blocks (unchanged): BK=64, global_load_lds
// staging, XOR-swizzled source + swizzled ds_read, 2-phase double-buffer
// with counted vmcnt(8).
// ---------------------------------------------------------------------------
#define GEMM_STAGE(dstA, dstB, Aptr, Bptr, k0)                                  \
    {                                                                           \
        _Pragma("unroll")                                                       \
        for (int it = 0; it < 4; ++it) {                                        \
            int i = (w * 4 + it) * 64 + lane;                                   \
            int row = i >> 3, p = i & 7;                                        \
            int gc = (k0) + ((p ^ (row & 7)) << 3);                             \
            gload_lds16((Aptr) + (size_t)(m0 + row) * K + gc,                   \
                        (dstA) + (w * 4 + it) * 512);                           \
        }                                                                       \
        _Pragma("unroll")                                                       \
        for (int it = 0; it < 4; ++it) {                                        \
            int i = (w * 4 + it) * 64 + lane;                                   \
            int row = i >> 3, p = i & 7;                                        \
            int gc = (k0) + ((p ^ (row & 7)) << 3);                             \
            gload_lds16((Bptr) + (size_t)(n0 + row) * K + gc,                   \
                        (dstB) + (w * 4 + it) * 512);                           \
        }                                                                       \
    }

#define GEMM_COMPUTE(srcA, srcB)                                                \
    {                                                                           \
        _Pragma("unroll")                                                       \
        for (int ks = 0; ks < 2; ++ks) {                                        \
            short8_t af[4], bf[4];                                              \
            _Pragma("unroll")                                                   \
            for (int mt = 0; mt < 4; ++mt) {                                    \
                int r = wm * 64 + mt * 16 + l16;                                \
                int g = ks * 4 + quad;                                          \
                af[mt] = *(const short8_t*)&(srcA)[r * 64 + ((g ^ (r & 7)) << 3)]; \
            }                                                                   \
            _Pragma("unroll")                                                   \
            for (int nt = 0; nt < 4; ++nt) {                                    \
                int r = wn * 64 + nt * 16 + l16;                                \
                int g = ks * 4 + quad;                                          \
                bf[nt] = *(const short8_t*)&(srcB)[r * 64 + ((g ^ (r & 7)) << 3)]; \
            }                                                                   \
            _Pragma("unroll")                                                   \
            for (int mt = 0; mt < 4; ++mt)                                      \
                _Pragma("unroll")                                               \
                for (int nt = 0; nt < 4; ++nt)                                  \
                    acc[mt][nt] = __builtin_amdgcn_mfma_f32_16x16x32_bf16(      \
                        af[mt], bf[nt], acc[mt][nt], 0, 0, 0);                  \
        }                                                                       \
    }

#define GEMM_KLOOP(Aptr, Bptr)                                                  \
    GEMM_STAGE(sA(0), sB(0), Aptr, Bptr, 0);                                    \
    for (int t = 0; t < NT; ++t) {                                              \
        int cur = t & 1;                                                        \
        if (t + 1 < NT) {                                                       \
            GEMM_STAGE(sA(cur ^ 1), sB(cur ^ 1), Aptr, Bptr, (t + 1) * 64);     \
            asm volatile("s_waitcnt vmcnt(8)" ::: "memory");                    \
        } else {                                                                \
            asm volatile("s_waitcnt vmcnt(0)" ::: "memory");                    \
        }                                                                       \
        __builtin_amdgcn_s_barrier();                                           \
        __builtin_amdgcn_sched_barrier(0);                                      \
        GEMM_COMPUTE(sA(cur), sB(cur));                                         \
        __builtin_amdgcn_sched_barrier(0);                                      \
        __builtin_amdgcn_s_barrier();                                           \
    }

// ---------------------------------------------------------------------------
// QKV GEMM (unchanged from R11): 128x128 tile, counted-vmcnt 2-phase,
// XCD-aware block swizzle.
// ---------------------------------------------------------------------------
__global__ __launch_bounds__(256) void gemm_qkv(
    const short* __restrict__ A, const short* __restrict__ Bt,
    const float* __restrict__ bias, const float2* __restrict__ Tab,
    short* __restrict__ QKVb, short* __restrict__ Vt)
{
    __shared__ __align__(16) short smem[32768];     // 64 KB: 2 x (A 8K | B 8K)
    #define sA(b) (smem + (b) * 16384)
    #define sB(b) (smem + (b) * 16384 + 8192)

    const int K = C_DIM, NT = C_DIM / 64;
    // XCD swizzle: 384 blocks, 48 per XCD, decode x-major (12 col-blocks)
    int bid = blockIdx.x;
    int swz = (bid & 7) * 48 + (bid >> 3);
    int m0 = (swz / 12) * 128;
    int n0 = (swz % 12) * 128;
    int tid  = threadIdx.x;
    int w    = tid >> 6, lane = tid & 63;
    int quad = lane >> 4, l16 = lane & 15;
    int wm = w & 1, wn = w >> 1;

    f32x4 acc[4][4] = {};

    GEMM_KLOOP(A, Bt);

    if (n0 < 1280) {
        // Q or K: bias + RoPE (+ Q_SCALE for Q)
        float scale = (n0 < 1024) ? Q_SCALE : 1.0f;
        float sgn   = (l16 & 1) ? 1.0f : -1.0f;
        #pragma unroll
        for (int nt = 0; nt < 4; ++nt) {
            int col = n0 + wn * 64 + nt * 16 + l16;
            int ip  = (col & 63) >> 1;
            float bv = bias[col];
            #pragma unroll
            for (int mt = 0; mt < 4; ++mt) {
                #pragma unroll
                for (int r = 0; r < 4; ++r) {
                    int row = m0 + wm * 64 + mt * 16 + quad * 4 + r;
                    float v = acc[mt][nt][r] + bv;
                    float po = dpp_xor1(v);
                    float2 cs = Tab[(row & (T_SEQ - 1)) * 32 + ip];
                    float res = (v * cs.x + sgn * po * cs.y) * scale;
                    QKVb[(size_t)row * QKVW + col] = f2bs(res);
                }
            }
        }
    } else {
        // V: bias + transpose -> Vt[d][token], two 64-dim passes through LDS
        short (*sT)[136] = (short(*)[136])smem;    // 64 x 136 shorts
        #pragma unroll
        for (int h2 = 0; h2 < 2; ++h2) {
            if (wn == h2) {
                #pragma unroll
                for (int nt = 0; nt < 4; ++nt) {
                    int col_l = nt * 16 + l16;             // 0..63
                    float bv = bias[n0 + h2 * 64 + col_l];
                    #pragma unroll
                    for (int mt = 0; mt < 4; ++mt)
                        #pragma unroll
                        for (int r = 0; r < 4; ++r)
                            sT[col_l][wm * 64 + mt * 16 + quad * 4 + r] =
                                f2bs(acc[mt][nt][r] + bv);
                }
            }
            __syncthreads();
            int d0 = n0 - 1280 + h2 * 64;
            #pragma unroll
            for (int it = 0; it < 4; ++it) {
                int slot = tid + 256 * it;                 // 64 dims x 16 segs
                int dl = slot >> 4, seg = (slot & 15) * 8;
                *(short8_t*)(Vt + (size_t)(d0 + dl) * MTOK + m0 + seg) =
                    *(const short8_t*)&sT[dl][seg];
            }
            __syncthreads();
        }
    }
    #undef sA
    #undef sB
}

// ---------------------------------------------------------------------------
// O-projection GEMM (unchanged from R11): 128x128 tile, counted-vmcnt
// 2-phase, XCD swizzle.
// ---------------------------------------------------------------------------
__global__ __launch_bounds__(256) void gemm_mfma_o(
    const short* __restrict__ A, const short* __restrict__ Bt,
    const float* __restrict__ bias, float* __restrict__ C,
    int M, int N, int K_, int unused)
{
    __shared__ __align__(16) short smem[32768];
    #define sA(b) (smem + (b) * 16384)
    #define sB(b) (smem + (b) * 16384 + 8192)

    const int K = C_DIM, NT = C_DIM / 64;
    int bid = blockIdx.x;
    int swz = (bid & 7) * 32 + (bid >> 3);
    int m0 = (swz >> 3) * 128;
    int n0 = (swz & 7) * 128;
    int tid  = threadIdx.x;
    int w    = tid >> 6, lane = tid & 63;
    int quad = lane >> 4, l16 = lane & 15;
    int wm = w & 1, wn = w >> 1;

    f32x4 acc[4][4] = {};

    GEMM_KLOOP(A, Bt);

    #pragma unroll
    for (int mt = 0; mt < 4; ++mt) {
        #pragma unroll
        for (int nt = 0; nt < 4; ++nt) {
            int col = n0 + wn * 64 + nt * 16 + l16;
            float bv = bias[col];
            #pragma unroll
            for (int r = 0; r < 4; ++r) {
                int row = m0 + wm * 64 + mt * 16 + quad * 4 + r;
                C[(size_t)row * N + col] = acc[mt][nt][r] + bv;
            }
        }
    }
    #undef sA
    #undef sB
}

// ---------------------------------------------------------------------------
// MFMA flash attention v18 = v17 + 3-BUFFER K RING + COUNTED-VMCNT BARRIERS.
// v17's __syncthreads drained vmcnt(0) every region, but K(c+1) was issued
// only ONE region before its use — its L2/HBM latency had ~1 region of
// softmax+PV to hide under, with the residual exposed at every barrier.
// v18: K ring of 3 buffers (K(c) in sK3[c%3]); K(c+3) issued in region c
// (dest = buffer c%3, whose QK(c)-reads finished in region c-1). Barriers
// are raw s_barrier with COUNTED waits (T4):
//   B_c: need K(c+1) done; in flight: K(c+2) {iter c-1}, vr(c+1) {iter c-1}
//     c+2<=ct: vmcnt(2) | c+1<=ct (ct==c+1): vmcnt(1) | else: lgkm only
//   lgkmcnt(0) always (V ds_write visibility); sched_barrier(0) after.
// Prologue issues K(0..2), waits vmcnt(3/2/0) by ct. K DMA now has TWO full
// regions to complete -> barrier wait ~0. V path unchanged (compiler-managed).
// Anti-correlated pair mapping (R11) and the rest of v17 kept verbatim.
// ---------------------------------------------------------------------------
__global__ __launch_bounds__(512) void attn_mfma18(
    const short* __restrict__ QKV, const short* __restrict__ Vt,
    short* __restrict__ O)
{
    __shared__ __align__(16) short sK3[3][64][64];   // swizzled granules ring
    __shared__ __align__(16) short sVt[2][64][72];   // padded, perm'd tokens

    const int tid  = threadIdx.x;          // 0..511
    const int w    = tid >> 6;             // 0..7
    const int lane = tid & 63;
    const int quad = lane >> 4;
    const int l16  = lane & 15;

    int blk = blockIdx.x;
    int grp = blk & 7;                     // (b,kvh)
    // anti-correlated pair mapping: first half long pairs, second half short
    int half = blk >> 8;                   // 0 or 1
    int idx8 = (blk & 255) >> 3;           // 0..31
    int pr   = half ? idx8 : 63 - idx8;    // [63..32] then [0..31]
    int kvh = grp & 3;
    int b   = grp >> 2;
    int h   = kvh * 4 + (w & 3);
    int tq  = pr * 2 + (w >> 2);           // waves 0-3: tile A, 4-7: tile B
    int ct  = pr >> 1;                     // == tq>>2 for both tiles
    int tg  = tq * 16 + l16;

    // Q frags (already roped + scaled)
    const short* qptr = QKV + ((size_t)(b * T_SEQ) + tq * 16 + l16) * QKVW + h * HD;
    short8_t qf0 = *(const short8_t*)(qptr + quad * 8);
    short8_t qf1 = *(const short8_t*)(qptr + quad * 8 + 32);

    const short* kbase  = QKV + (size_t)b * T_SEQ * QKVW + 1024 + kvh * HD;
    const short* vtbase = Vt + (size_t)(kvh * HD) * MTOK + b * T_SEQ;

    float m_l = -INFINITY, l_l = 0.f;      // quad-partial row sum
    f32x4 oacc[4];
    #pragma unroll
    for (int dt = 0; dt < 4; ++dt) oacc[dt] = (f32x4){0.f, 0.f, 0.f, 0.f};

    // K DMA staging indices (512 threads cover the 64x64 tile, 16B each)
    const int kr_  = tid >> 3;              // row 0..63
    const int kg   = tid & 7;               // dest granule
    const int ksrc = (kg ^ (kr_ & 7)) << 3; // pre-swizzled source col

    // V reg staging indices (512 threads cover the 64x64 tile)
    const int vdim = tid >> 3;              // 0..63
    const int s8   = tid & 7;
    const int vseg = s8 * 8;
    const int P0   = ((s8 & 4) << 3) | ((s8 & 1) << 4) | ((s8 & 2) << 1);

    // swizzled K read granule (row&7 == l16&7 since rows are l16+16kt)
    const int c0g = quad ^ (l16 & 7);

    // ---- prologue ----
    // v0 FIRST so its ds_write wait (vmcnt leaves later K DMAs in flight)
    short8_t v0 = *(const short8_t*)(vtbase + (size_t)vdim * MTOK + vseg);
    gload_lds16(kbase + (size_t)kr_ * QKVW + ksrc, (short*)sK3[0] + (w << 9));
    if (ct >= 1)
        gload_lds16(kbase + (size_t)(64 + kr_) * QKVW + ksrc,
                    (short*)sK3[1] + (w << 9));
    if (ct >= 2)
        gload_lds16(kbase + (size_t)(128 + kr_) * QKVW + ksrc,
                    (short*)sK3[2] + (w << 9));
    {
        union { short8_t v; short4_t h[2]; } u; u.v = v0;
        *(short4_t*)&sVt[0][vdim][P0]     = u.h[0];
        *(short4_t*)&sVt[0][vdim][P0 + 8] = u.h[1];
    }
    short8_t vr;
    if (ct > 0)
        vr = *(const short8_t*)(vtbase + (size_t)vdim * MTOK + 64 + vseg);
    // wait K(0) done; leave K(1),K(2),vr in flight
    if (ct >= 2)      asm volatile("s_waitcnt vmcnt(3) lgkmcnt(0)" ::: "memory");
    else if (ct == 1) asm volatile("s_waitcnt vmcnt(2) lgkmcnt(0)" ::: "memory");
    else              asm volatile("s_waitcnt vmcnt(0) lgkmcnt(0)" ::: "memory");
    __builtin_amdgcn_s_barrier();
    __builtin_amdgcn_sched_barrier(0);

    f32x4 sacc[4], sacc_n[4];
    #pragma unroll
    for (int kt = 0; kt < 4; ++kt) {
        f32x4 z = {0.f, 0.f, 0.f, 0.f};
        const short* krow = &sK3[0][l16 + 16 * kt][0];
        short8_t kf0 = *(const short8_t*)(krow + (c0g << 3));
        short8_t kf1 = *(const short8_t*)(krow + ((c0g ^ 4) << 3));
        z = __builtin_amdgcn_mfma_f32_16x16x32_bf16(kf0, qf0, z, 0, 0, 0);
        z = __builtin_amdgcn_mfma_f32_16x16x32_bf16(kf1, qf1, z, 0, 0, 0);
        sacc[kt] = z;
    }

    int kc = 0;                            // c % 3
    for (int c = 0; c <= ct; ++c) {
        const int buf = c & 1;
        const int kn  = (kc == 2) ? 0 : kc + 1;   // (c+1) % 3

        // B_c: counted wait (never drain mid-loop), lgkm for V visibility
        if (c + 2 <= ct)      asm volatile("s_waitcnt vmcnt(2) lgkmcnt(0)" ::: "memory");
        else if (c + 1 <= ct) asm volatile("s_waitcnt vmcnt(1) lgkmcnt(0)" ::: "memory");
        else                  asm volatile("s_waitcnt lgkmcnt(0)" ::: "memory");
        __builtin_amdgcn_s_barrier();
        __builtin_amdgcn_sched_barrier(0);

        __builtin_amdgcn_s_setprio(1);
        // QK(c+1): independent MFMA stream — interleaves with softmax(c)
        if (c < ct) {
            #pragma unroll
            for (int kt = 0; kt < 4; ++kt) {
                f32x4 z = {0.f, 0.f, 0.f, 0.f};
                const short* krow = &sK3[kn][l16 + 16 * kt][0];
                short8_t kf0 = *(const short8_t*)(krow + (c0g << 3));
                short8_t kf1 = *(const short8_t*)(krow + ((c0g ^ 4) << 3));
                z = __builtin_amdgcn_mfma_f32_16x16x32_bf16(kf0, qf0, z, 0, 0, 0);
                z = __builtin_amdgcn_mfma_f32_16x16x32_bf16(kf1, qf1, z, 0, 0, 0);
                sacc_n[kt] = z;
            }
            // K(c+3) DMA into buffer c%3 (K(c)'s reads finished in region c-1)
            if (c + 3 <= ct) {
                int jn = (c + 3) * 64;
                gload_lds16(kbase + (size_t)(jn + kr_) * QKVW + ksrc,
                            (short*)sK3[kc] + (w << 9));
            }
        }

        // mask the CURRENT chunk's scores on the causal diagonal
        if (c == ct) {
            int j0 = c * 64;
            #pragma unroll
            for (int kt = 0; kt < 4; ++kt)
                #pragma unroll
                for (int r = 0; r < 4; ++r)
                    if (j0 + 16 * kt + quad * 4 + r > tg) sacc[kt][r] = -INFINITY;
        }

        // ---- softmax(c) on sacc (VALU; overlaps QK(c+1) MFMAs) ----
        float v0s = fmaxf(fmaxf(sacc[0][0], sacc[0][1]), fmaxf(sacc[0][2], sacc[0][3]));
        float v1s = fmaxf(fmaxf(sacc[1][0], sacc[1][1]), fmaxf(sacc[1][2], sacc[1][3]));
        float v2s = fmaxf(fmaxf(sacc[2][0], sacc[2][1]), fmaxf(sacc[2][2], sacc[2][3]));
        float v3s = fmaxf(fmaxf(sacc[3][0], sacc[3][1]), fmaxf(sacc[3][2], sacc[3][3]));
        float vloc = fmaxf(fmaxf(v0s, v1s), fmaxf(v2s, v3s));

        if (!__all(vloc <= m_l + 8.0f)) {
            float vmax = fmaxf(vloc, __shfl_xor(vloc, 16));
            vmax = fmaxf(vmax, __shfl_xor(vmax, 32));
            float mnew = fmaxf(m_l, vmax);
            float al = fast_exp2(m_l - mnew);
            m_l = mnew;
            l_l *= al;
            #pragma unroll
            for (int r = 0; r < 4; ++r) {
                float alr = __shfl(al, quad * 4 + r);
                #pragma unroll
                for (int dt = 0; dt < 4; ++dt) oacc[dt][r] *= alr;
            }
        }

        float psum = 0.f;
        unsigned pk0, pk1, pk2, pk3, pk4, pk5, pk6, pk7;
        {
            float p0 = fast_exp2(sacc[0][0] - m_l), p1 = fast_exp2(sacc[0][1] - m_l);
            float p2 = fast_exp2(sacc[0][2] - m_l), p3 = fast_exp2(sacc[0][3] - m_l);
            psum += (p0 + p1) + (p2 + p3);
            pk0 = pack_bf16_trunc(p0, p1); pk1 = pack_bf16_trunc(p2, p3);
        }
        {
            float p0 = fast_exp2(sacc[1][0] - m_l), p1 = fast_exp2(sacc[1][1] - m_l);
            float p2 = fast_exp2(sacc[1][2] - m_l), p3 = fast_exp2(sacc[1][3] - m_l);
            psum += (p0 + p1) + (p2 + p3);
            pk2 = pack_bf16_trunc(p0, p1); pk3 = pack_bf16_trunc(p2, p3);
        }
        {
            float p0 = fast_exp2(sacc[2][0] - m_l), p1 = fast_exp2(sacc[2][1] - m_l);
            float p2 = fast_exp2(sacc[2][2] - m_l), p3 = fast_exp2(sacc[2][3] - m_l);
            psum += (p0 + p1) + (p2 + p3);
            pk4 = pack_bf16_trunc(p0, p1); pk5 = pack_bf16_trunc(p2, p3);
        }
        {
            float p0 = fast_exp2(sacc[3][0] - m_l), p1 = fast_exp2(sacc[3][1] - m_l);
            float p2 = fast_exp2(sacc[3][2] - m_l), p3 = fast_exp2(sacc[3][3] - m_l);
            psum += (p0 + p1) + (p2 + p3);
            pk6 = pack_bf16_trunc(p0, p1); pk7 = pack_bf16_trunc(p2, p3);
        }
        l_l += psum;

        short8_t pf0, pf1;
        {
            union { unsigned u[4]; short8_t v; } fa, fb;
            fa.u[0] = pk0; fa.u[1] = pk1; fa.u[2] = pk2; fa.u[3] = pk3;
            fb.u[0] = pk4; fb.u[1] = pk5; fb.u[2] = pk6; fb.u[3] = pk7;
            pf0 = fa.v; pf1 = fb.v;
        }

        // V(c+1) write + V(c+2) load issue (hidden under PV)
        if (c < ct) {
            union { short8_t v; short4_t hh[2]; } u; u.v = vr;
            *(short4_t*)&sVt[buf ^ 1][vdim][P0]     = u.hh[0];
            *(short4_t*)&sVt[buf ^ 1][vdim][P0 + 8] = u.hh[1];
            if (c + 2 <= ct)
                vr = *(const short8_t*)(vtbase + (size_t)vdim * MTOK
                                        + (c + 2) * 64 + vseg);
        }

        // ---- PV(c) ----
        #pragma unroll
        for (int dt = 0; dt < 4; ++dt) {
            short8_t vf0 = *(const short8_t*)&sVt[buf][16 * dt + l16][quad * 8];
            short8_t vf1 = *(const short8_t*)&sVt[buf][16 * dt + l16][quad * 8 + 32];
            oacc[dt] = __builtin_amdgcn_mfma_f32_16x16x32_bf16(pf0, vf0, oacc[dt], 0, 0, 0);
            oacc[dt] = __builtin_amdgcn_mfma_f32_16x16x32_bf16(pf1, vf1, oacc[dt], 0, 0, 0);
        }
        __builtin_amdgcn_s_setprio(0);

        // rotate S-tiles and K-ring index
        #pragma unroll
        for (int kt = 0; kt < 4; ++kt) sacc[kt] = sacc_n[kt];
        kc = kn;
    }

    l_l += __shfl_xor(l_l, 16);
    l_l += __shfl_xor(l_l, 32);

    #pragma unroll
    for (int r = 0; r < 4; ++r) {
        int m = quad * 4 + r;
        float lr = __shfl(l_l, quad * 4 + r);
        float inv = __builtin_amdgcn_rcpf(lr);
        #pragma unroll
        for (int dt = 0; dt < 4; ++dt)
            O[((size_t)b * T_SEQ + tq * 16 + m) * C_DIM + h * HD + 16 * dt + l16] =
                f2bs(oacc[dt][r] * inv);
    }
}

// ---------------------------------------------------------------------------
extern "C" void kernel_launch(void* const* d_in, const int* in_sizes, int n_in,
                              void* d_out, int out_size, void* d_ws, size_t ws_size,
                              hipStream_t stream)
{
    const float* x   = (const float*)d_in[0];
    const float* w_q = (const float*)d_in[1];
    const float* b_q = (const float*)d_in[2];
    const float* w_k = (const float*)d_in[3];
    const float* b_k = (const float*)d_in[4];
    const float* w_v = (const float*)d_in[5];
    const float* b_v = (const float*)d_in[6];
    const float* w_o = (const float*)d_in[7];
    const float* b_o = (const float*)d_in[8];
    float* out = (float*)d_out;

    char* ws = (char*)d_ws;
    short*  Xb   = (short*) (ws);                              // 8 MB
    short*  Ab   = (short*) (ws + ((size_t)8  << 20));         // 8 MB
    short*  QKVb = (short*) (ws + ((size_t)16 << 20));         // 12 MB
    short*  Wqkv = (short*) (ws + ((size_t)28 << 20));         // 3 MB
    short*  Wto  = (short*) (ws + ((size_t)31 << 20));         // 2 MB
    float*  Bqkv = (float*) (ws + ((size_t)33 << 20));         // 6 KB
    float2* Tab  = (float2*)(ws + ((size_t)33 << 20) + 8192);  // 512 KB
    short*  Vt   = (short*) (ws + ((size_t)34 << 20));         // 2 MB

    const int M = MTOK;   // 4096

    prep_kernel<<<6918, 256, 0, stream>>>(
        x, w_q, w_k, w_v, w_o, b_q, b_k, b_v, Xb, Wqkv, Wto, Bqkv, Tab);

    gemm_qkv<<<384, 256, 0, stream>>>(
        Xb, Wqkv, Bqkv, Tab, QKVb, Vt);

    attn_mfma18<<<B_SZ * NKV * 64, 512, 0, stream>>>(QKVb, Vt, Ab);

    gemm_mfma_o<<<256, 256, 0, stream>>>(
        Ab, Wto, b_o, out, M, C_DIM, C_DIM, 0);
}